// Round 15
// baseline (67.144 us; speedup 1.0000x reference)
//
#include <hip/hip_runtime.h>
#include <hip/hip_bf16.h>
#include <hip/hip_fp16.h>
#include <math.h>

#define B 256
#define S 128
#define E 768
#define E4 192      // E/4 (float4 per row)
#define NA 30
#define NNEG 10

#define K2_KC 96    // k-chunk per block; ksplit = 8

__device__ __forceinline__ float dot4(float4 a, float4 b) {
    return a.x * b.x + a.y * b.y + a.z * b.z + a.w * b.w;
}
__device__ __forceinline__ float wave_reduce_sum(float v) {
#pragma unroll
    for (int off = 32; off; off >>= 1) v += __shfl_down(v, off);
    return v;   // valid on lane 0
}
__device__ __forceinline__ float wave_reduce_max(float v) {
#pragma unroll
    for (int off = 32; off; off >>= 1) v = fmaxf(v, __shfl_down(v, off));
    return v;   // valid on lane 0
}
__device__ __forceinline__ float4 h4_to_f4(uint2 p) {
    __half2* ph = (__half2*)&p;
    float2 f0 = __half22float2(ph[0]);
    float2 f1 = __half22float2(ph[1]);
    return make_float4(f0.x, f0.y, f1.x, f1.y);
}

// ---------------- K1: q-partials (2 per b) + fp16 x-copy + 30 prep blocks ----------------
template <int USE16>
__global__ __launch_bounds__(768) void mean_prep_kernel(const float* __restrict__ x,
                                                        const float* __restrict__ W_red,
                                                        const float* __restrict__ aspect_W,
                                                        float* __restrict__ q,      // [2][B][E]
                                                        float* __restrict__ WredT,
                                                        float* __restrict__ invn,
                                                        __half* __restrict__ xh) {
    int bid = blockIdx.x;
    int tid = threadIdx.x;
    __shared__ __align__(16) float4 part[4][E4];
    __shared__ float red[12];

    if (bid < 2 * B) {
        int b = bid >> 1, half = bid & 1;
        int c = tid % E4;     // float4 column
        int g = tid / E4;     // 0..3 (s-subgroup)
        const float4* xb = (const float4*)(x + (size_t)b * S * E);
        uint2* xhb = (uint2*)(xh + (size_t)b * S * E);
        int s0 = half * 64 + g * 16;
        float4 acc = make_float4(0.f, 0.f, 0.f, 0.f);
#pragma unroll 4
        for (int s = s0; s < s0 + 16; ++s) {
            float4 v = xb[(size_t)s * E4 + c];
            acc.x += v.x; acc.y += v.y; acc.z += v.z; acc.w += v.w;
            if (USE16) {
                __half2 h01 = __floats2half2_rn(v.x, v.y);
                __half2 h23 = __floats2half2_rn(v.z, v.w);
                uint2 pk;
                pk.x = *(unsigned int*)&h01;
                pk.y = *(unsigned int*)&h23;
                xhb[(size_t)s * E4 + c] = pk;
            }
        }
        part[g][c] = acc;
        __syncthreads();
        if (tid < E4) {
            float4 a0 = part[0][c], a1 = part[1][c], a2 = part[2][c], a3 = part[3][c];
            const float inv = 1.0f / (float)S;      // halves sum to the mean
            float4 r;
            r.x = (a0.x + a1.x + a2.x + a3.x) * inv;
            r.y = (a0.y + a1.y + a2.y + a3.y) * inv;
            r.z = (a0.z + a1.z + a2.z + a3.z) * inv;
            r.w = (a0.w + a1.w + a2.w + a3.w) * inv;
            ((float4*)q)[((size_t)half * B + b) * E4 + c] = r;
        }
    } else {
        int a = bid - 2 * B;                       // 0..29
        WredT[(size_t)a * E + tid] = W_red[(size_t)tid * NA + a];
        int wave = tid >> 6, lane = tid & 63;
        float v = aspect_W[(size_t)a * E + tid];
        float ss = wave_reduce_sum(v * v);
        if (lane == 0) red[wave] = ss;
        __syncthreads();
        if (tid == 0) {
            float n = 0.f;
#pragma unroll
            for (int w = 0; w < 12; ++w) n += red[w];
            invn[a] = 1.0f / fmaxf(sqrtf(n), 1e-12f);
        }
    }
}

// ---------------- K2: qW partials (k-split 8 GEMM; sums the 2 q-halves in-stage) ----------------
__global__ __launch_bounds__(256) void qw_partial_kernel(const float* __restrict__ q,   // [2][B][E]
                                                         const float* __restrict__ W_att,
                                                         float* __restrict__ part) {   // [8][B][E]
    int b0 = blockIdx.x * 64;
    int e0 = blockIdx.y * 64;
    int kz = blockIdx.z;
    int k0 = kz * K2_KC;
    int tid = threadIdx.x;

    __shared__ __align__(16) float qs[64][K2_KC + 4];
    __shared__ __align__(16) float ws[K2_KC][64];

    int r0 = (tid >> 3) * 2;
    int c0 = (tid & 7) * 8;

    float4 a00 = make_float4(0,0,0,0), a01 = make_float4(0,0,0,0);
    float4 a10 = make_float4(0,0,0,0), a11 = make_float4(0,0,0,0);

    {
        int row = tid >> 2, ks = (tid & 3) * 24;
        const float* src0 = q + (size_t)(b0 + row) * E + k0 + ks;
        const float* src1 = src0 + (size_t)B * E;
#pragma unroll
        for (int j = 0; j < 6; ++j) {
            float4 v0 = *(const float4*)(src0 + 4 * j);
            float4 v1 = *(const float4*)(src1 + 4 * j);
            v0.x += v1.x; v0.y += v1.y; v0.z += v1.z; v0.w += v1.w;
            *(float4*)&qs[row][ks + 4 * j] = v0;
        }
    }
    for (int i = tid; i < K2_KC * 16; i += 256) {
        int row = i >> 4, e4 = (i & 15) * 4;
        *(float4*)&ws[row][e4] =
            *(const float4*)(W_att + (size_t)(k0 + row) * E + e0 + e4);
    }
    __syncthreads();
#pragma unroll 4
    for (int k = 0; k < K2_KC; ++k) {
        float qa = qs[r0][k], qb = qs[r0 + 1][k];
        float4 w0 = *(const float4*)&ws[k][c0];
        float4 w1 = *(const float4*)&ws[k][c0 + 4];
        a00.x += qa * w0.x; a00.y += qa * w0.y; a00.z += qa * w0.z; a00.w += qa * w0.w;
        a01.x += qa * w1.x; a01.y += qa * w1.y; a01.z += qa * w1.z; a01.w += qa * w1.w;
        a10.x += qb * w0.x; a10.y += qb * w0.y; a10.z += qb * w0.z; a10.w += qb * w0.w;
        a11.x += qb * w1.x; a11.y += qb * w1.y; a11.z += qb * w1.z; a11.w += qb * w1.w;
    }
    float* dst = part + ((size_t)kz * B + b0 + r0) * E + e0 + c0;
    *(float4*)dst = a00; *(float4*)(dst + 4) = a01;
    *(float4*)(dst + E) = a10; *(float4*)(dst + E + 4) = a11;
}

// ---------------- K3: s-half online-softmax attention (2 blocks/b) + 30 ortho blocks ----------------
// Block (b,h): 8 waves x 8 rows of half h. Writes UNNORMALIZED (m,l,z-partial) to ws.
template <int USE16>
__global__ __launch_bounds__(512) void attn_half_kernel(const float* __restrict__ x,
                                                        const __half* __restrict__ xh,
                                                        const float* __restrict__ part,   // [8][B][E]
                                                        const float* __restrict__ b_att,
                                                        const float* __restrict__ aspect_W,
                                                        const float* __restrict__ invn,
                                                        float* __restrict__ zhalf,        // [B*2][E]
                                                        float* __restrict__ mh,           // [B*2]
                                                        float* __restrict__ lh,           // [B*2]
                                                        float* __restrict__ Gpart) {
    int bid = blockIdx.x;
    int tid = threadIdx.x, wave = tid >> 6, lane = tid & 63;
    __shared__ __align__(16) float4 qw4[E4];       // attn: qW[b]; ortho: normalized row i
    __shared__ __align__(16) float4 zw[8][E4];     // per-wave z partials (24 KB)
    __shared__ float wm[8], wl[8];
    __shared__ float red[8];

    if (bid >= 2 * B) {
        // ---- ortho block (8 waves): row i of G = Tn Tn^T - I ----
        int i = bid - 2 * B;
        float inv_i = invn[i];
        if (tid < E4) {
            float4 v = ((const float4*)aspect_W)[(size_t)i * E4 + tid];
            v.x *= inv_i; v.y *= inv_i; v.z *= inv_i; v.w *= inv_i;
            qw4[tid] = v;
        }
        __syncthreads();
        float acc = 0.f;
        for (int j = wave; j < NA; j += 8) {
            const float4* aj = (const float4*)(aspect_W + (size_t)j * E);
            float d = 0.f;
#pragma unroll
            for (int jj = 0; jj < 3; ++jj)
                d += dot4(aj[lane + 64 * jj], qw4[lane + 64 * jj]);
            d = wave_reduce_sum(d);
            if (lane == 0) {
                float g = d * invn[j] - ((i == j) ? 1.f : 0.f);
                acc += g * g;
            }
        }
        if (lane == 0) red[wave] = acc;
        __syncthreads();
        if (tid == 0) {
            float s = 0.f;
#pragma unroll
            for (int w = 0; w < 8; ++w) s += red[w];
            Gpart[i] = s;
        }
        return;
    }

    int b = bid >> 1, h = bid & 1;
    const int N4 = B * E / 4;
    // stage qW[b] = sum of 8 k-partials + b_att
    if (tid < E4) {
        const float4* p = (const float4*)part;
        size_t base = (size_t)b * E4 + tid;
        float4 r = ((const float4*)b_att)[tid];
#pragma unroll
        for (int i = 0; i < 8; ++i) {
            float4 s = p[base + (size_t)i * N4];
            r.x += s.x; r.y += s.y; r.z += s.z; r.w += s.w;
        }
        qw4[tid] = r;
    }
    __syncthreads();

    float4 q0 = qw4[lane], q1 = qw4[lane + 64], q2 = qw4[lane + 128];

    // two independent online-softmax chains over this wave's 8 rows
    float m0 = -3.4e38f, l0 = 0.f, m1 = -3.4e38f, l1 = 0.f;
    float4 p00 = make_float4(0.f,0.f,0.f,0.f), p01 = p00, p02 = p00;
    float4 p10 = p00, p11 = p00, p12 = p00;

    const uint2*  xhb = (const uint2*)(xh + (size_t)b * S * E);
    const float4* xb  = (const float4*)(x + (size_t)b * S * E);
    int s0 = h * 64 + wave * 8;

#pragma unroll
    for (int i = 0; i < 8; i += 4) {
        float4 xA0, xA1, xA2, xB0, xB1, xB2, xC0, xC1, xC2, xD0, xD1, xD2;
        if (USE16) {
            const uint2* rA = xhb + (size_t)(s0 + i) * E4;
            const uint2* rB = rA + E4;
            const uint2* rC = rB + E4;
            const uint2* rD = rC + E4;
            xA0 = h4_to_f4(rA[lane]); xA1 = h4_to_f4(rA[lane + 64]); xA2 = h4_to_f4(rA[lane + 128]);
            xB0 = h4_to_f4(rB[lane]); xB1 = h4_to_f4(rB[lane + 64]); xB2 = h4_to_f4(rB[lane + 128]);
            xC0 = h4_to_f4(rC[lane]); xC1 = h4_to_f4(rC[lane + 64]); xC2 = h4_to_f4(rC[lane + 128]);
            xD0 = h4_to_f4(rD[lane]); xD1 = h4_to_f4(rD[lane + 64]); xD2 = h4_to_f4(rD[lane + 128]);
        } else {
            const float4* rA = xb + (size_t)(s0 + i) * E4;
            const float4* rB = rA + E4;
            const float4* rC = rB + E4;
            const float4* rD = rC + E4;
            xA0 = rA[lane]; xA1 = rA[lane + 64]; xA2 = rA[lane + 128];
            xB0 = rB[lane]; xB1 = rB[lane + 64]; xB2 = rB[lane + 128];
            xC0 = rC[lane]; xC1 = rC[lane + 64]; xC2 = rC[lane + 128];
            xD0 = rD[lane]; xD1 = rD[lane + 64]; xD2 = rD[lane + 128];
        }
        float dA = dot4(xA0, q0) + dot4(xA1, q1) + dot4(xA2, q2);
        float dB = dot4(xB0, q0) + dot4(xB1, q1) + dot4(xB2, q2);
        float dC = dot4(xC0, q0) + dot4(xC1, q1) + dot4(xC2, q2);
        float dD = dot4(xD0, q0) + dot4(xD1, q1) + dot4(xD2, q2);
#pragma unroll
        for (int off = 32; off; off >>= 1) {
            dA += __shfl_xor(dA, off);
            dB += __shfl_xor(dB, off);
            dC += __shfl_xor(dC, off);
            dD += __shfl_xor(dD, off);
        }
        float tm0 = fmaxf(m0, fmaxf(dA, dB));
        float sc0 = __expf(m0 - tm0);
        float eA = __expf(dA - tm0), eB = __expf(dB - tm0);
        float tm1 = fmaxf(m1, fmaxf(dC, dD));
        float sc1 = __expf(m1 - tm1);
        float eC = __expf(dC - tm1), eD = __expf(dD - tm1);

        l0 = l0 * sc0 + eA + eB;
        l1 = l1 * sc1 + eC + eD;
        p00.x = p00.x * sc0 + eA * xA0.x + eB * xB0.x;
        p00.y = p00.y * sc0 + eA * xA0.y + eB * xB0.y;
        p00.z = p00.z * sc0 + eA * xA0.z + eB * xB0.z;
        p00.w = p00.w * sc0 + eA * xA0.w + eB * xB0.w;
        p10.x = p10.x * sc1 + eC * xC0.x + eD * xD0.x;
        p10.y = p10.y * sc1 + eC * xC0.y + eD * xD0.y;
        p10.z = p10.z * sc1 + eC * xC0.z + eD * xD0.z;
        p10.w = p10.w * sc1 + eC * xC0.w + eD * xD0.w;
        p01.x = p01.x * sc0 + eA * xA1.x + eB * xB1.x;
        p01.y = p01.y * sc0 + eA * xA1.y + eB * xB1.y;
        p01.z = p01.z * sc0 + eA * xA1.z + eB * xB1.z;
        p01.w = p01.w * sc0 + eA * xA1.w + eB * xB1.w;
        p11.x = p11.x * sc1 + eC * xC1.x + eD * xD1.x;
        p11.y = p11.y * sc1 + eC * xC1.y + eD * xD1.y;
        p11.z = p11.z * sc1 + eC * xC1.z + eD * xD1.z;
        p11.w = p11.w * sc1 + eC * xC1.w + eD * xD1.w;
        p02.x = p02.x * sc0 + eA * xA2.x + eB * xB2.x;
        p02.y = p02.y * sc0 + eA * xA2.y + eB * xB2.y;
        p02.z = p02.z * sc0 + eA * xA2.z + eB * xB2.z;
        p02.w = p02.w * sc0 + eA * xA2.w + eB * xB2.w;
        p12.x = p12.x * sc1 + eC * xC2.x + eD * xD2.x;
        p12.y = p12.y * sc1 + eC * xC2.y + eD * xD2.y;
        p12.z = p12.z * sc1 + eC * xC2.z + eD * xD2.z;
        p12.w = p12.w * sc1 + eC * xC2.w + eD * xD2.w;
        m0 = tm0;
        m1 = tm1;
    }

    // merge the two chains (exact rescale)
    float m = fmaxf(m0, m1);
    float f0 = __expf(m0 - m), f1 = __expf(m1 - m);
    float l = l0 * f0 + l1 * f1;
    float4 a0, a1, a2;
    a0.x = p00.x * f0 + p10.x * f1; a0.y = p00.y * f0 + p10.y * f1;
    a0.z = p00.z * f0 + p10.z * f1; a0.w = p00.w * f0 + p10.w * f1;
    a1.x = p01.x * f0 + p11.x * f1; a1.y = p01.y * f0 + p11.y * f1;
    a1.z = p01.z * f0 + p11.z * f1; a1.w = p01.w * f0 + p11.w * f1;
    a2.x = p02.x * f0 + p12.x * f1; a2.y = p02.y * f0 + p12.y * f1;
    a2.z = p02.z * f0 + p12.z * f1; a2.w = p02.w * f0 + p12.w * f1;

    zw[wave][lane] = a0;
    zw[wave][lane + 64] = a1;
    zw[wave][lane + 128] = a2;
    if (lane == 0) { wm[wave] = m; wl[wave] = l; }
    __syncthreads();

    // combine 8 waves (UNNORMALIZED output for this half)
    if (tid < E4) {
        float M = wm[0];
#pragma unroll
        for (int w = 1; w < 8; ++w) M = fmaxf(M, wm[w]);
        float L = 0.f;
        float4 z = make_float4(0.f, 0.f, 0.f, 0.f);
#pragma unroll
        for (int w = 0; w < 8; ++w) {
            float f = __expf(wm[w] - M);
            float4 a = zw[w][tid];
            z.x += f * a.x; z.y += f * a.y; z.z += f * a.z; z.w += f * a.w;
            L += f * wl[w];
        }
        ((float4*)zhalf)[(size_t)bid * E4 + tid] = z;
        if (tid == 0) { mh[bid] = M; lh[bid] = L; }
    }
}

// ---------------- K3b: combine the two s-halves -> z_s ----------------
__global__ __launch_bounds__(192) void zcombine_kernel(const float* __restrict__ zhalf,
                                                       const float* __restrict__ mh,
                                                       const float* __restrict__ lh,
                                                       float* __restrict__ z_s) {
    int b = blockIdx.x;
    int tid = threadIdx.x;          // 0..191
    float m0 = mh[2 * b], m1 = mh[2 * b + 1];
    float M = fmaxf(m0, m1);
    float f0 = __expf(m0 - M), f1 = __expf(m1 - M);
    float L = f0 * lh[2 * b] + f1 * lh[2 * b + 1];
    float invL = 1.0f / L;
    float4 z0 = ((const float4*)zhalf)[(size_t)(2 * b) * E4 + tid];
    float4 z1 = ((const float4*)zhalf)[(size_t)(2 * b + 1) * E4 + tid];
    float4 z;
    z.x = (f0 * z0.x + f1 * z1.x) * invL;
    z.y = (f0 * z0.y + f1 * z1.y) * invL;
    z.z = (f0 * z0.z + f1 * z1.z) * invL;
    z.w = (f0 * z0.w + f1 * z1.w) * invL;
    ((float4*)z_s)[(size_t)b * E4 + tid] = z;
}

// ---------------- K4: composition + reconstruction + margin (768 thr) ----------------
__global__ __launch_bounds__(768) void recon_margin_kernel(const float* __restrict__ z_s,
                                                           const float* __restrict__ WredT,
                                                           const float* __restrict__ b_red,
                                                           const float* __restrict__ aspect_W,
                                                           const int* __restrict__ neg_idx,
                                                           float* __restrict__ recon,
                                                           float* __restrict__ mpart) {
    int b = blockIdx.x;
    int tid = threadIdx.x, wave = tid >> 6, lane = tid & 63;
    __shared__ __align__(16) float4 z4[E4];
    __shared__ float comp[NA];
    __shared__ __align__(16) float r_sh[E];
    __shared__ float red[12];
    __shared__ float dots[12];

    if (tid < E4) z4[tid] = ((const float4*)(z_s + (size_t)b * E))[tid];
    __syncthreads();

    for (int a = wave; a < NA; a += 12) {
        const float4* wr = (const float4*)(WredT + (size_t)a * E);
        float d = 0.f;
#pragma unroll
        for (int j = 0; j < 3; ++j)
            d += dot4(wr[lane + 64 * j], z4[lane + 64 * j]);
        d = wave_reduce_sum(d);
        if (lane == 0) comp[a] = d + b_red[a];
    }
    __syncthreads();

    if (wave == 0) {
        float v = (lane < NA) ? comp[lane] : -3.4e38f;
        float m = wave_reduce_max(v);
        m = __shfl(m, 0);
        float e = (lane < NA) ? expf(v - m) : 0.f;
        float ssum = wave_reduce_sum(e);
        ssum = __shfl(ssum, 0);
        if (lane < NA) comp[lane] = e / ssum;
    }
    __syncthreads();

    float r = 0.f;
    for (int a = 0; a < NA; ++a)
        r += comp[a] * aspect_W[(size_t)a * E + tid];
    recon[(size_t)b * E + tid] = r;
    r_sh[tid] = r;
    float sq = wave_reduce_sum(r * r);
    if (lane == 0) red[wave] = sq;
    __syncthreads();
    float tot = 0.f;
#pragma unroll
    for (int w = 0; w < 12; ++w) tot += red[w];
    float inv = 1.0f / fmaxf(sqrtf(tot), 1e-12f);

    if (wave <= NNEG) {
        int row = (wave == 0) ? b : neg_idx[b * NNEG + (wave - 1)];
        const float4* zr = (const float4*)(z_s + (size_t)row * E);
        const float4* rr = (const float4*)r_sh;
        float acc = 0.f;
#pragma unroll
        for (int j = 0; j < 3; ++j)
            acc += dot4(zr[lane + 64 * j], rr[lane + 64 * j]);
        acc = wave_reduce_sum(acc);
        if (lane == 0) dots[wave] = acc;
    }
    __syncthreads();
    if (tid == 0) {
        float pos = dots[0] * inv;
        float ssum = 0.f;
        for (int n = 1; n <= NNEG; ++n)
            ssum += fmaxf(1.f - pos + dots[n] * inv, 0.f);
        mpart[b] = ssum;
    }
}

// ---------------- K5: final scalar loss ----------------
__global__ __launch_bounds__(256) void loss_kernel(const float* __restrict__ Gpart,
                                                   const float* __restrict__ mpart,
                                                   float* __restrict__ loss_out) {
    int tid = threadIdx.x, wave = tid >> 6, lane = tid & 63;
    __shared__ float ra[4], rb[4];
    float fr = (tid < NA) ? Gpart[tid] : 0.f;
    fr = wave_reduce_sum(fr);
    if (lane == 0) ra[wave] = fr;
    float mp = mpart[tid];
    mp = wave_reduce_sum(mp);
    if (lane == 0) rb[wave] = mp;
    __syncthreads();
    if (tid == 0) {
        float frob = sqrtf(ra[0] + ra[1] + ra[2] + ra[3]);
        float msum = rb[0] + rb[1] + rb[2] + rb[3];
        loss_out[0] = frob + msum * (1.0f / (float)(B * NNEG));
    }
}

extern "C" void kernel_launch(void* const* d_in, const int* in_sizes, int n_in,
                              void* d_out, int out_size, void* d_ws, size_t ws_size,
                              hipStream_t stream) {
    const float* x        = (const float*)d_in[0];
    const float* W_att    = (const float*)d_in[1];
    const float* b_att    = (const float*)d_in[2];
    const float* W_red    = (const float*)d_in[3];
    const float* b_red    = (const float*)d_in[4];
    const float* aspect_W = (const float*)d_in[5];
    const int*   neg_idx  = (const int*)d_in[6];

    float* out   = (float*)d_out;
    float* z_s   = out;                       // [B,E]
    float* recon = out + (size_t)B * E;       // [B,E]
    float* loss  = out + (size_t)2 * B * E;   // [1]

    float* ws    = (float*)d_ws;
    float* q     = ws;                         // 2*B*E
    float* part2 = q + (size_t)2 * B * E;      // 8*B*E
    float* WredT = part2 + (size_t)8 * B * E;  // NA*E
    float* invn  = WredT + (size_t)NA * E;     // 32
    float* Gpart = invn + 32;                  // 32
    float* mpart = Gpart + 32;                 // B
    float* zhalf = mpart + B;                  // 2*B*E
    float* mh    = zhalf + (size_t)2 * B * E;  // 2*B
    float* lhv   = mh + 2 * B;                 // 2*B
    float* endf  = lhv + 2 * B;

    size_t base_floats = (size_t)(endf - ws);
    size_t need = base_floats * sizeof(float) + (size_t)B * S * E * sizeof(__half);
    bool use16 = (ws_size >= need);
    __half* xh = (__half*)(ws + base_floats);

    if (use16) {
        mean_prep_kernel<1><<<2 * B + NA, 768, 0, stream>>>(x, W_red, aspect_W, q, WredT, invn, xh);
        qw_partial_kernel<<<dim3(4, 12, 8), 256, 0, stream>>>(q, W_att, part2);
        attn_half_kernel<1><<<2 * B + NA, 512, 0, stream>>>(x, xh, part2, b_att, aspect_W, invn,
                                                            zhalf, mh, lhv, Gpart);
    } else {
        mean_prep_kernel<0><<<2 * B + NA, 768, 0, stream>>>(x, W_red, aspect_W, q, WredT, invn, xh);
        qw_partial_kernel<<<dim3(4, 12, 8), 256, 0, stream>>>(q, W_att, part2);
        attn_half_kernel<0><<<2 * B + NA, 512, 0, stream>>>(x, xh, part2, b_att, aspect_W, invn,
                                                            zhalf, mh, lhv, Gpart);
    }
    zcombine_kernel<<<B, 192, 0, stream>>>(zhalf, mh, lhv, z_s);
    recon_margin_kernel<<<B, 768, 0, stream>>>(z_s, WredT, b_red, aspect_W, neg_idx, recon, mpart);
    loss_kernel<<<1, 256, 0, stream>>>(Gpart, mpart, loss);
}

// Round 16
// 64.065 us; speedup vs baseline: 1.0481x; 1.0481x over previous
//
#include <hip/hip_runtime.h>
#include <hip/hip_bf16.h>
#include <hip/hip_fp16.h>
#include <math.h>

#define B 256
#define S 128
#define E 768
#define E4 192      // E/4 (float4 per row)
#define NA 30
#define NNEG 10

#define K2_KC 96    // k-chunk per block; ksplit = 8

__device__ __forceinline__ float dot4(float4 a, float4 b) {
    return a.x * b.x + a.y * b.y + a.z * b.z + a.w * b.w;
}
__device__ __forceinline__ float wave_reduce_sum(float v) {
#pragma unroll
    for (int off = 32; off; off >>= 1) v += __shfl_down(v, off);
    return v;   // valid on lane 0
}
__device__ __forceinline__ float wave_reduce_max(float v) {
#pragma unroll
    for (int off = 32; off; off >>= 1) v = fmaxf(v, __shfl_down(v, off));
    return v;   // valid on lane 0
}
__device__ __forceinline__ float4 h4_to_f4(uint2 p) {
    __half2* ph = (__half2*)&p;
    float2 f0 = __half22float2(ph[0]);
    float2 f1 = __half22float2(ph[1]);
    return make_float4(f0.x, f0.y, f1.x, f1.y);
}

// ---------------- K1: q-partials (2 per b) + fp16 x-copy + 30 prep blocks ----------------
template <int USE16>
__global__ __launch_bounds__(768) void mean_prep_kernel(const float* __restrict__ x,
                                                        const float* __restrict__ W_red,
                                                        const float* __restrict__ aspect_W,
                                                        float* __restrict__ q,      // [2][B][E]
                                                        float* __restrict__ WredT,
                                                        float* __restrict__ invn,
                                                        __half* __restrict__ xh) {
    int bid = blockIdx.x;
    int tid = threadIdx.x;
    __shared__ __align__(16) float4 part[4][E4];
    __shared__ float red[12];

    if (bid < 2 * B) {
        int b = bid >> 1, half = bid & 1;
        int c = tid % E4;     // float4 column
        int g = tid / E4;     // 0..3 (s-subgroup)
        const float4* xb = (const float4*)(x + (size_t)b * S * E);
        uint2* xhb = (uint2*)(xh + (size_t)b * S * E);
        int s0 = half * 64 + g * 16;
        float4 acc = make_float4(0.f, 0.f, 0.f, 0.f);
#pragma unroll 4
        for (int s = s0; s < s0 + 16; ++s) {
            float4 v = xb[(size_t)s * E4 + c];
            acc.x += v.x; acc.y += v.y; acc.z += v.z; acc.w += v.w;
            if (USE16) {
                __half2 h01 = __floats2half2_rn(v.x, v.y);
                __half2 h23 = __floats2half2_rn(v.z, v.w);
                uint2 pk;
                pk.x = *(unsigned int*)&h01;
                pk.y = *(unsigned int*)&h23;
                xhb[(size_t)s * E4 + c] = pk;
            }
        }
        part[g][c] = acc;
        __syncthreads();
        if (tid < E4) {
            float4 a0 = part[0][c], a1 = part[1][c], a2 = part[2][c], a3 = part[3][c];
            const float inv = 1.0f / (float)S;      // halves sum to the mean
            float4 r;
            r.x = (a0.x + a1.x + a2.x + a3.x) * inv;
            r.y = (a0.y + a1.y + a2.y + a3.y) * inv;
            r.z = (a0.z + a1.z + a2.z + a3.z) * inv;
            r.w = (a0.w + a1.w + a2.w + a3.w) * inv;
            ((float4*)q)[((size_t)half * B + b) * E4 + c] = r;
        }
    } else {
        int a = bid - 2 * B;                       // 0..29
        WredT[(size_t)a * E + tid] = W_red[(size_t)tid * NA + a];
        int wave = tid >> 6, lane = tid & 63;
        float v = aspect_W[(size_t)a * E + tid];
        float ss = wave_reduce_sum(v * v);
        if (lane == 0) red[wave] = ss;
        __syncthreads();
        if (tid == 0) {
            float n = 0.f;
#pragma unroll
            for (int w = 0; w < 12; ++w) n += red[w];
            invn[a] = 1.0f / fmaxf(sqrtf(n), 1e-12f);
        }
    }
}

// ---------------- K2: qW partials (k-split 8 GEMM; sums the 2 q-halves in-stage) ----------------
__global__ __launch_bounds__(256) void qw_partial_kernel(const float* __restrict__ q,   // [2][B][E]
                                                         const float* __restrict__ W_att,
                                                         float* __restrict__ part) {   // [8][B][E]
    int b0 = blockIdx.x * 64;
    int e0 = blockIdx.y * 64;
    int kz = blockIdx.z;
    int k0 = kz * K2_KC;
    int tid = threadIdx.x;

    __shared__ __align__(16) float qs[64][K2_KC + 4];
    __shared__ __align__(16) float ws[K2_KC][64];

    int r0 = (tid >> 3) * 2;
    int c0 = (tid & 7) * 8;

    float4 a00 = make_float4(0,0,0,0), a01 = make_float4(0,0,0,0);
    float4 a10 = make_float4(0,0,0,0), a11 = make_float4(0,0,0,0);

    {
        int row = tid >> 2, ks = (tid & 3) * 24;
        const float* src0 = q + (size_t)(b0 + row) * E + k0 + ks;
        const float* src1 = src0 + (size_t)B * E;
#pragma unroll
        for (int j = 0; j < 6; ++j) {
            float4 v0 = *(const float4*)(src0 + 4 * j);
            float4 v1 = *(const float4*)(src1 + 4 * j);
            v0.x += v1.x; v0.y += v1.y; v0.z += v1.z; v0.w += v1.w;
            *(float4*)&qs[row][ks + 4 * j] = v0;
        }
    }
    for (int i = tid; i < K2_KC * 16; i += 256) {
        int row = i >> 4, e4 = (i & 15) * 4;
        *(float4*)&ws[row][e4] =
            *(const float4*)(W_att + (size_t)(k0 + row) * E + e0 + e4);
    }
    __syncthreads();
#pragma unroll 4
    for (int k = 0; k < K2_KC; ++k) {
        float qa = qs[r0][k], qb = qs[r0 + 1][k];
        float4 w0 = *(const float4*)&ws[k][c0];
        float4 w1 = *(const float4*)&ws[k][c0 + 4];
        a00.x += qa * w0.x; a00.y += qa * w0.y; a00.z += qa * w0.z; a00.w += qa * w0.w;
        a01.x += qa * w1.x; a01.y += qa * w1.y; a01.z += qa * w1.z; a01.w += qa * w1.w;
        a10.x += qb * w0.x; a10.y += qb * w0.y; a10.z += qb * w0.z; a10.w += qb * w0.w;
        a11.x += qb * w1.x; a11.y += qb * w1.y; a11.z += qb * w1.z; a11.w += qb * w1.w;
    }
    float* dst = part + ((size_t)kz * B + b0 + r0) * E + e0 + c0;
    *(float4*)dst = a00; *(float4*)(dst + 4) = a01;
    *(float4*)(dst + E) = a10; *(float4*)(dst + E + 4) = a11;
}

// ---------------- K3: single-sweep online-softmax attention, QUAD chains + 30 ortho blocks ----------------
template <int USE16>
__global__ __launch_bounds__(512) void attn_ortho_kernel(const float* __restrict__ x,
                                                         const __half* __restrict__ xh,
                                                         const float* __restrict__ part,   // [8][B][E]
                                                         const float* __restrict__ b_att,
                                                         const float* __restrict__ aspect_W,
                                                         const float* __restrict__ invn,
                                                         float* __restrict__ z_s,
                                                         float* __restrict__ Gpart) {
    int bid = blockIdx.x;
    int tid = threadIdx.x, wave = tid >> 6, lane = tid & 63;
    __shared__ __align__(16) float4 qw4[E4];       // attn: qW[b]; ortho: normalized row i
    __shared__ __align__(16) float4 zw[8][E4];     // per-wave z partials (24 KB)
    __shared__ float wm[8], wl[8];
    __shared__ float red[8];

    if (bid >= B) {
        // ---- ortho block (8 waves): row i of G = Tn Tn^T - I ----
        int i = bid - B;
        float inv_i = invn[i];
        if (tid < E4) {
            float4 v = ((const float4*)aspect_W)[(size_t)i * E4 + tid];
            v.x *= inv_i; v.y *= inv_i; v.z *= inv_i; v.w *= inv_i;
            qw4[tid] = v;
        }
        __syncthreads();
        float acc = 0.f;
        for (int j = wave; j < NA; j += 8) {
            const float4* aj = (const float4*)(aspect_W + (size_t)j * E);
            float d = 0.f;
#pragma unroll
            for (int jj = 0; jj < 3; ++jj)
                d += dot4(aj[lane + 64 * jj], qw4[lane + 64 * jj]);
            d = wave_reduce_sum(d);
            if (lane == 0) {
                float g = d * invn[j] - ((i == j) ? 1.f : 0.f);
                acc += g * g;
            }
        }
        if (lane == 0) red[wave] = acc;
        __syncthreads();
        if (tid == 0) {
            float s = 0.f;
#pragma unroll
            for (int w = 0; w < 8; ++w) s += red[w];
            Gpart[i] = s;
        }
        return;
    }

    int b = bid;
    const int N4 = B * E / 4;
    // stage qW[b] = sum of 8 k-partials + b_att
    if (tid < E4) {
        const float4* p = (const float4*)part;
        size_t base = (size_t)b * E4 + tid;
        float4 r = ((const float4*)b_att)[tid];
#pragma unroll
        for (int i = 0; i < 8; ++i) {
            float4 s = p[base + (size_t)i * N4];
            r.x += s.x; r.y += s.y; r.z += s.z; r.w += s.w;
        }
        qw4[tid] = r;
    }
    __syncthreads();

    // per-lane qW fragment in registers
    float4 q0 = qw4[lane], q1 = qw4[lane + 64], q2 = qw4[lane + 128];

    // FOUR independent online-softmax chains (2 rows each per iteration, 2 iterations)
    float m0 = -3.4e38f, l0 = 0.f, m1 = -3.4e38f, l1 = 0.f;
    float m2 = -3.4e38f, l2 = 0.f, m3 = -3.4e38f, l3 = 0.f;
    float4 z00 = make_float4(0.f,0.f,0.f,0.f), z01 = z00, z02 = z00;   // chain 0
    float4 z10 = z00, z11 = z00, z12 = z00;                            // chain 1
    float4 z20 = z00, z21 = z00, z22 = z00;                            // chain 2
    float4 z30 = z00, z31 = z00, z32 = z00;                            // chain 3

    const uint2*  xhb = (const uint2*)(xh + (size_t)b * S * E);
    const float4* xb  = (const float4*)(x + (size_t)b * S * E);
    int s0 = wave * 16;

#pragma unroll
    for (int i = 0; i < 16; i += 8) {
        float4 xA0,xA1,xA2, xB0,xB1,xB2, xC0,xC1,xC2, xD0,xD1,xD2;
        float4 xE0,xE1,xE2, xF0,xF1,xF2, xG0,xG1,xG2, xH0,xH1,xH2;
        if (USE16) {
            const uint2* rA = xhb + (size_t)(s0 + i) * E4;
            const uint2* rB = rA + E4;  const uint2* rC = rB + E4;  const uint2* rD = rC + E4;
            const uint2* rE = rD + E4;  const uint2* rF = rE + E4;  const uint2* rG = rF + E4;
            const uint2* rH = rG + E4;
            xA0 = h4_to_f4(rA[lane]); xA1 = h4_to_f4(rA[lane + 64]); xA2 = h4_to_f4(rA[lane + 128]);
            xB0 = h4_to_f4(rB[lane]); xB1 = h4_to_f4(rB[lane + 64]); xB2 = h4_to_f4(rB[lane + 128]);
            xC0 = h4_to_f4(rC[lane]); xC1 = h4_to_f4(rC[lane + 64]); xC2 = h4_to_f4(rC[lane + 128]);
            xD0 = h4_to_f4(rD[lane]); xD1 = h4_to_f4(rD[lane + 64]); xD2 = h4_to_f4(rD[lane + 128]);
            xE0 = h4_to_f4(rE[lane]); xE1 = h4_to_f4(rE[lane + 64]); xE2 = h4_to_f4(rE[lane + 128]);
            xF0 = h4_to_f4(rF[lane]); xF1 = h4_to_f4(rF[lane + 64]); xF2 = h4_to_f4(rF[lane + 128]);
            xG0 = h4_to_f4(rG[lane]); xG1 = h4_to_f4(rG[lane + 64]); xG2 = h4_to_f4(rG[lane + 128]);
            xH0 = h4_to_f4(rH[lane]); xH1 = h4_to_f4(rH[lane + 64]); xH2 = h4_to_f4(rH[lane + 128]);
        } else {
            const float4* rA = xb + (size_t)(s0 + i) * E4;
            const float4* rB = rA + E4;  const float4* rC = rB + E4;  const float4* rD = rC + E4;
            const float4* rE = rD + E4;  const float4* rF = rE + E4;  const float4* rG = rF + E4;
            const float4* rH = rG + E4;
            xA0 = rA[lane]; xA1 = rA[lane + 64]; xA2 = rA[lane + 128];
            xB0 = rB[lane]; xB1 = rB[lane + 64]; xB2 = rB[lane + 128];
            xC0 = rC[lane]; xC1 = rC[lane + 64]; xC2 = rC[lane + 128];
            xD0 = rD[lane]; xD1 = rD[lane + 64]; xD2 = rD[lane + 128];
            xE0 = rE[lane]; xE1 = rE[lane + 64]; xE2 = rE[lane + 128];
            xF0 = rF[lane]; xF1 = rF[lane + 64]; xF2 = rF[lane + 128];
            xG0 = rG[lane]; xG1 = rG[lane + 64]; xG2 = rG[lane + 128];
            xH0 = rH[lane]; xH1 = rH[lane + 64]; xH2 = rH[lane + 128];
        }
        float dA = dot4(xA0, q0) + dot4(xA1, q1) + dot4(xA2, q2);
        float dB = dot4(xB0, q0) + dot4(xB1, q1) + dot4(xB2, q2);
        float dC = dot4(xC0, q0) + dot4(xC1, q1) + dot4(xC2, q2);
        float dD = dot4(xD0, q0) + dot4(xD1, q1) + dot4(xD2, q2);
        float dE = dot4(xE0, q0) + dot4(xE1, q1) + dot4(xE2, q2);
        float dF = dot4(xF0, q0) + dot4(xF1, q1) + dot4(xF2, q2);
        float dG = dot4(xG0, q0) + dot4(xG1, q1) + dot4(xG2, q2);
        float dH = dot4(xH0, q0) + dot4(xH1, q1) + dot4(xH2, q2);
#pragma unroll
        for (int off = 32; off; off >>= 1) {
            dA += __shfl_xor(dA, off);
            dB += __shfl_xor(dB, off);
            dC += __shfl_xor(dC, off);
            dD += __shfl_xor(dD, off);
            dE += __shfl_xor(dE, off);
            dF += __shfl_xor(dF, off);
            dG += __shfl_xor(dG, off);
            dH += __shfl_xor(dH, off);
        }
        // four independent chain updates
        float tm0 = fmaxf(m0, fmaxf(dA, dB));
        float sc0 = __expf(m0 - tm0);
        float eA = __expf(dA - tm0), eB = __expf(dB - tm0);
        float tm1 = fmaxf(m1, fmaxf(dC, dD));
        float sc1 = __expf(m1 - tm1);
        float eC = __expf(dC - tm1), eD = __expf(dD - tm1);
        float tm2 = fmaxf(m2, fmaxf(dE, dF));
        float sc2 = __expf(m2 - tm2);
        float eE = __expf(dE - tm2), eF = __expf(dF - tm2);
        float tm3 = fmaxf(m3, fmaxf(dG, dH));
        float sc3 = __expf(m3 - tm3);
        float eG = __expf(dG - tm3), eH = __expf(dH - tm3);

        l0 = l0 * sc0 + eA + eB;
        l1 = l1 * sc1 + eC + eD;
        l2 = l2 * sc2 + eE + eF;
        l3 = l3 * sc3 + eG + eH;

        z00.x = z00.x * sc0 + eA * xA0.x + eB * xB0.x;
        z00.y = z00.y * sc0 + eA * xA0.y + eB * xB0.y;
        z00.z = z00.z * sc0 + eA * xA0.z + eB * xB0.z;
        z00.w = z00.w * sc0 + eA * xA0.w + eB * xB0.w;
        z01.x = z01.x * sc0 + eA * xA1.x + eB * xB1.x;
        z01.y = z01.y * sc0 + eA * xA1.y + eB * xB1.y;
        z01.z = z01.z * sc0 + eA * xA1.z + eB * xB1.z;
        z01.w = z01.w * sc0 + eA * xA1.w + eB * xB1.w;
        z02.x = z02.x * sc0 + eA * xA2.x + eB * xB2.x;
        z02.y = z02.y * sc0 + eA * xA2.y + eB * xB2.y;
        z02.z = z02.z * sc0 + eA * xA2.z + eB * xB2.z;
        z02.w = z02.w * sc0 + eA * xA2.w + eB * xB2.w;

        z10.x = z10.x * sc1 + eC * xC0.x + eD * xD0.x;
        z10.y = z10.y * sc1 + eC * xC0.y + eD * xD0.y;
        z10.z = z10.z * sc1 + eC * xC0.z + eD * xD0.z;
        z10.w = z10.w * sc1 + eC * xC0.w + eD * xD0.w;
        z11.x = z11.x * sc1 + eC * xC1.x + eD * xD1.x;
        z11.y = z11.y * sc1 + eC * xC1.y + eD * xD1.y;
        z11.z = z11.z * sc1 + eC * xC1.z + eD * xD1.z;
        z11.w = z11.w * sc1 + eC * xC1.w + eD * xD1.w;
        z12.x = z12.x * sc1 + eC * xC2.x + eD * xD2.x;
        z12.y = z12.y * sc1 + eC * xC2.y + eD * xD2.y;
        z12.z = z12.z * sc1 + eC * xC2.z + eD * xD2.z;
        z12.w = z12.w * sc1 + eC * xC2.w + eD * xD2.w;

        z20.x = z20.x * sc2 + eE * xE0.x + eF * xF0.x;
        z20.y = z20.y * sc2 + eE * xE0.y + eF * xF0.y;
        z20.z = z20.z * sc2 + eE * xE0.z + eF * xF0.z;
        z20.w = z20.w * sc2 + eE * xE0.w + eF * xF0.w;
        z21.x = z21.x * sc2 + eE * xE1.x + eF * xF1.x;
        z21.y = z21.y * sc2 + eE * xE1.y + eF * xF1.y;
        z21.z = z21.z * sc2 + eE * xE1.z + eF * xF1.z;
        z21.w = z21.w * sc2 + eE * xE1.w + eF * xF1.w;
        z22.x = z22.x * sc2 + eE * xE2.x + eF * xF2.x;
        z22.y = z22.y * sc2 + eE * xE2.y + eF * xF2.y;
        z22.z = z22.z * sc2 + eE * xE2.z + eF * xF2.z;
        z22.w = z22.w * sc2 + eE * xE2.w + eF * xF2.w;

        z30.x = z30.x * sc3 + eG * xG0.x + eH * xH0.x;
        z30.y = z30.y * sc3 + eG * xG0.y + eH * xH0.y;
        z30.z = z30.z * sc3 + eG * xG0.z + eH * xH0.z;
        z30.w = z30.w * sc3 + eG * xG0.w + eH * xH0.w;
        z31.x = z31.x * sc3 + eG * xG1.x + eH * xH1.x;
        z31.y = z31.y * sc3 + eG * xG1.y + eH * xH1.y;
        z31.z = z31.z * sc3 + eG * xG1.z + eH * xH1.z;
        z31.w = z31.w * sc3 + eG * xG1.w + eH * xH1.w;
        z32.x = z32.x * sc3 + eG * xG2.x + eH * xH2.x;
        z32.y = z32.y * sc3 + eG * xG2.y + eH * xH2.y;
        z32.z = z32.z * sc3 + eG * xG2.z + eH * xH2.z;
        z32.w = z32.w * sc3 + eG * xG2.w + eH * xH2.w;

        m0 = tm0; m1 = tm1; m2 = tm2; m3 = tm3;
    }

    // pairwise exact merges: (0,1) -> A, (2,3) -> B, then (A,B)
    float mA = fmaxf(m0, m1);
    float fA0 = __expf(m0 - mA), fA1 = __expf(m1 - mA);
    float lA = l0 * fA0 + l1 * fA1;
    float4 A0, A1, A2;
    A0.x = z00.x * fA0 + z10.x * fA1; A0.y = z00.y * fA0 + z10.y * fA1;
    A0.z = z00.z * fA0 + z10.z * fA1; A0.w = z00.w * fA0 + z10.w * fA1;
    A1.x = z01.x * fA0 + z11.x * fA1; A1.y = z01.y * fA0 + z11.y * fA1;
    A1.z = z01.z * fA0 + z11.z * fA1; A1.w = z01.w * fA0 + z11.w * fA1;
    A2.x = z02.x * fA0 + z12.x * fA1; A2.y = z02.y * fA0 + z12.y * fA1;
    A2.z = z02.z * fA0 + z12.z * fA1; A2.w = z02.w * fA0 + z12.w * fA1;

    float mB = fmaxf(m2, m3);
    float fB0 = __expf(m2 - mB), fB1 = __expf(m3 - mB);
    float lB = l2 * fB0 + l3 * fB1;
    float4 B0, B1, B2;
    B0.x = z20.x * fB0 + z30.x * fB1; B0.y = z20.y * fB0 + z30.y * fB1;
    B0.z = z20.z * fB0 + z30.z * fB1; B0.w = z20.w * fB0 + z30.w * fB1;
    B1.x = z21.x * fB0 + z31.x * fB1; B1.y = z21.y * fB0 + z31.y * fB1;
    B1.z = z21.z * fB0 + z31.z * fB1; B1.w = z21.w * fB0 + z31.w * fB1;
    B2.x = z22.x * fB0 + z32.x * fB1; B2.y = z22.y * fB0 + z32.y * fB1;
    B2.z = z22.z * fB0 + z32.z * fB1; B2.w = z22.w * fB0 + z32.w * fB1;

    float m = fmaxf(mA, mB);
    float f0 = __expf(mA - m), f1 = __expf(mB - m);
    float l = lA * f0 + lB * f1;
    float4 a0, a1, a2;
    a0.x = A0.x * f0 + B0.x * f1; a0.y = A0.y * f0 + B0.y * f1;
    a0.z = A0.z * f0 + B0.z * f1; a0.w = A0.w * f0 + B0.w * f1;
    a1.x = A1.x * f0 + B1.x * f1; a1.y = A1.y * f0 + B1.y * f1;
    a1.z = A1.z * f0 + B1.z * f1; a1.w = A1.w * f0 + B1.w * f1;
    a2.x = A2.x * f0 + B2.x * f1; a2.y = A2.y * f0 + B2.y * f1;
    a2.z = A2.z * f0 + B2.z * f1; a2.w = A2.w * f0 + B2.w * f1;

    // per-wave partials to LDS
    zw[wave][lane] = a0;
    zw[wave][lane + 64] = a1;
    zw[wave][lane + 128] = a2;
    if (lane == 0) { wm[wave] = m; wl[wave] = l; }
    __syncthreads();

    // combine 8 waves with rescale (threads 0..191)
    if (tid < E4) {
        float M = wm[0];
#pragma unroll
        for (int w = 1; w < 8; ++w) M = fmaxf(M, wm[w]);
        float L = 0.f;
        float4 z = make_float4(0.f, 0.f, 0.f, 0.f);
#pragma unroll
        for (int w = 0; w < 8; ++w) {
            float f = __expf(wm[w] - M);
            float4 a = zw[w][tid];
            z.x += f * a.x; z.y += f * a.y; z.z += f * a.z; z.w += f * a.w;
            L += f * wl[w];
        }
        float invL = 1.0f / L;
        z.x *= invL; z.y *= invL; z.z *= invL; z.w *= invL;
        ((float4*)z_s)[(size_t)b * E4 + tid] = z;
    }
}

// ---------------- K4: composition + reconstruction + margin (768 thr) ----------------
__global__ __launch_bounds__(768) void recon_margin_kernel(const float* __restrict__ z_s,
                                                           const float* __restrict__ WredT,
                                                           const float* __restrict__ b_red,
                                                           const float* __restrict__ aspect_W,
                                                           const int* __restrict__ neg_idx,
                                                           float* __restrict__ recon,
                                                           float* __restrict__ mpart) {
    int b = blockIdx.x;
    int tid = threadIdx.x, wave = tid >> 6, lane = tid & 63;
    __shared__ __align__(16) float4 z4[E4];
    __shared__ float comp[NA];
    __shared__ __align__(16) float r_sh[E];
    __shared__ float red[12];
    __shared__ float dots[12];

    if (tid < E4) z4[tid] = ((const float4*)(z_s + (size_t)b * E))[tid];
    __syncthreads();

    for (int a = wave; a < NA; a += 12) {
        const float4* wr = (const float4*)(WredT + (size_t)a * E);
        float d = 0.f;
#pragma unroll
        for (int j = 0; j < 3; ++j)
            d += dot4(wr[lane + 64 * j], z4[lane + 64 * j]);
        d = wave_reduce_sum(d);
        if (lane == 0) comp[a] = d + b_red[a];
    }
    __syncthreads();

    if (wave == 0) {
        float v = (lane < NA) ? comp[lane] : -3.4e38f;
        float m = wave_reduce_max(v);
        m = __shfl(m, 0);
        float e = (lane < NA) ? expf(v - m) : 0.f;
        float ssum = wave_reduce_sum(e);
        ssum = __shfl(ssum, 0);
        if (lane < NA) comp[lane] = e / ssum;
    }
    __syncthreads();

    float r = 0.f;
    for (int a = 0; a < NA; ++a)
        r += comp[a] * aspect_W[(size_t)a * E + tid];
    recon[(size_t)b * E + tid] = r;
    r_sh[tid] = r;
    float sq = wave_reduce_sum(r * r);
    if (lane == 0) red[wave] = sq;
    __syncthreads();
    float tot = 0.f;
#pragma unroll
    for (int w = 0; w < 12; ++w) tot += red[w];
    float inv = 1.0f / fmaxf(sqrtf(tot), 1e-12f);

    if (wave <= NNEG) {
        int row = (wave == 0) ? b : neg_idx[b * NNEG + (wave - 1)];
        const float4* zr = (const float4*)(z_s + (size_t)row * E);
        const float4* rr = (const float4*)r_sh;
        float acc = 0.f;
#pragma unroll
        for (int j = 0; j < 3; ++j)
            acc += dot4(zr[lane + 64 * j], rr[lane + 64 * j]);
        acc = wave_reduce_sum(acc);
        if (lane == 0) dots[wave] = acc;
    }
    __syncthreads();
    if (tid == 0) {
        float pos = dots[0] * inv;
        float ssum = 0.f;
        for (int n = 1; n <= NNEG; ++n)
            ssum += fmaxf(1.f - pos + dots[n] * inv, 0.f);
        mpart[b] = ssum;
    }
}

// ---------------- K5: final scalar loss ----------------
__global__ __launch_bounds__(256) void loss_kernel(const float* __restrict__ Gpart,
                                                   const float* __restrict__ mpart,
                                                   float* __restrict__ loss_out) {
    int tid = threadIdx.x, wave = tid >> 6, lane = tid & 63;
    __shared__ float ra[4], rb[4];
    float fr = (tid < NA) ? Gpart[tid] : 0.f;
    fr = wave_reduce_sum(fr);
    if (lane == 0) ra[wave] = fr;
    float mp = mpart[tid];
    mp = wave_reduce_sum(mp);
    if (lane == 0) rb[wave] = mp;
    __syncthreads();
    if (tid == 0) {
        float frob = sqrtf(ra[0] + ra[1] + ra[2] + ra[3]);
        float msum = rb[0] + rb[1] + rb[2] + rb[3];
        loss_out[0] = frob + msum * (1.0f / (float)(B * NNEG));
    }
}

extern "C" void kernel_launch(void* const* d_in, const int* in_sizes, int n_in,
                              void* d_out, int out_size, void* d_ws, size_t ws_size,
                              hipStream_t stream) {
    const float* x        = (const float*)d_in[0];
    const float* W_att    = (const float*)d_in[1];
    const float* b_att    = (const float*)d_in[2];
    const float* W_red    = (const float*)d_in[3];
    const float* b_red    = (const float*)d_in[4];
    const float* aspect_W = (const float*)d_in[5];
    const int*   neg_idx  = (const int*)d_in[6];

    float* out   = (float*)d_out;
    float* z_s   = out;                       // [B,E]
    float* recon = out + (size_t)B * E;       // [B,E]
    float* loss  = out + (size_t)2 * B * E;   // [1]

    float* ws    = (float*)d_ws;
    float* q     = ws;                        // 2*B*E
    float* part2 = q + (size_t)2 * B * E;     // 8*B*E
    float* WredT = part2 + (size_t)8 * B * E; // NA*E
    float* invn  = WredT + (size_t)NA * E;    // 32
    float* Gpart = invn + 32;                 // 32
    float* mpart = Gpart + 32;                // B
    float* endf  = mpart + B;

    size_t base_floats = (size_t)(endf - ws);
    size_t need = base_floats * sizeof(float) + (size_t)B * S * E * sizeof(__half);
    bool use16 = (ws_size >= need);
    __half* xh = (__half*)(ws + base_floats);

    if (use16) {
        mean_prep_kernel<1><<<2 * B + NA, 768, 0, stream>>>(x, W_red, aspect_W, q, WredT, invn, xh);
        qw_partial_kernel<<<dim3(4, 12, 8), 256, 0, stream>>>(q, W_att, part2);
        attn_ortho_kernel<1><<<B + NA, 512, 0, stream>>>(x, xh, part2, b_att, aspect_W, invn, z_s, Gpart);
    } else {
        mean_prep_kernel<0><<<2 * B + NA, 768, 0, stream>>>(x, W_red, aspect_W, q, WredT, invn, xh);
        qw_partial_kernel<<<dim3(4, 12, 8), 256, 0, stream>>>(q, W_att, part2);
        attn_ortho_kernel<0><<<B + NA, 512, 0, stream>>>(x, xh, part2, b_att, aspect_W, invn, z_s, Gpart);
    }
    recon_margin_kernel<<<B, 768, 0, stream>>>(z_s, WredT, b_red, aspect_W, neg_idx, recon, mpart);
    loss_kernel<<<1, 256, 0, stream>>>(Gpart, mpart, loss);
}

// Round 17
// 63.810 us; speedup vs baseline: 1.0523x; 1.0040x over previous
//
#include <hip/hip_runtime.h>
#include <hip/hip_bf16.h>
#include <hip/hip_fp16.h>
#include <math.h>

#define B 256
#define S 128
#define E 768
#define E4 192      // E/4 (float4 per row)
#define NA 30
#define NNEG 10

#define K2_KC 96    // k-chunk per block; ksplit = 8

__device__ __forceinline__ float dot4(float4 a, float4 b) {
    return a.x * b.x + a.y * b.y + a.z * b.z + a.w * b.w;
}
__device__ __forceinline__ float wave_reduce_sum(float v) {
#pragma unroll
    for (int off = 32; off; off >>= 1) v += __shfl_down(v, off);
    return v;   // valid on lane 0
}
__device__ __forceinline__ float wave_reduce_max(float v) {
#pragma unroll
    for (int off = 32; off; off >>= 1) v = fmaxf(v, __shfl_down(v, off));
    return v;   // valid on lane 0
}
__device__ __forceinline__ float4 h4_to_f4(uint2 p) {
    __half2* ph = (__half2*)&p;
    float2 f0 = __half22float2(ph[0]);
    float2 f1 = __half22float2(ph[1]);
    return make_float4(f0.x, f0.y, f1.x, f1.y);
}

// ---------------- K1: q-partials (2 per b) + fp16 x-copy + 30 prep blocks ----------------
template <int USE16>
__global__ __launch_bounds__(768) void mean_prep_kernel(const float* __restrict__ x,
                                                        const float* __restrict__ W_red,
                                                        const float* __restrict__ aspect_W,
                                                        float* __restrict__ q,      // [2][B][E]
                                                        float* __restrict__ WredT,
                                                        float* __restrict__ invn,
                                                        __half* __restrict__ xh) {
    int bid = blockIdx.x;
    int tid = threadIdx.x;
    __shared__ __align__(16) float4 part[4][E4];
    __shared__ float red[12];

    if (bid < 2 * B) {
        int b = bid >> 1, half = bid & 1;
        int c = tid % E4;     // float4 column
        int g = tid / E4;     // 0..3 (s-subgroup)
        const float4* xb = (const float4*)(x + (size_t)b * S * E);
        uint2* xhb = (uint2*)(xh + (size_t)b * S * E);
        int s0 = half * 64 + g * 16;
        float4 acc = make_float4(0.f, 0.f, 0.f, 0.f);
#pragma unroll 4
        for (int s = s0; s < s0 + 16; ++s) {
            float4 v = xb[(size_t)s * E4 + c];
            acc.x += v.x; acc.y += v.y; acc.z += v.z; acc.w += v.w;
            if (USE16) {
                __half2 h01 = __floats2half2_rn(v.x, v.y);
                __half2 h23 = __floats2half2_rn(v.z, v.w);
                uint2 pk;
                pk.x = *(unsigned int*)&h01;
                pk.y = *(unsigned int*)&h23;
                xhb[(size_t)s * E4 + c] = pk;
            }
        }
        part[g][c] = acc;
        __syncthreads();
        if (tid < E4) {
            float4 a0 = part[0][c], a1 = part[1][c], a2 = part[2][c], a3 = part[3][c];
            const float inv = 1.0f / (float)S;      // halves sum to the mean
            float4 r;
            r.x = (a0.x + a1.x + a2.x + a3.x) * inv;
            r.y = (a0.y + a1.y + a2.y + a3.y) * inv;
            r.z = (a0.z + a1.z + a2.z + a3.z) * inv;
            r.w = (a0.w + a1.w + a2.w + a3.w) * inv;
            ((float4*)q)[((size_t)half * B + b) * E4 + c] = r;
        }
    } else {
        int a = bid - 2 * B;                       // 0..29
        WredT[(size_t)a * E + tid] = W_red[(size_t)tid * NA + a];
        int wave = tid >> 6, lane = tid & 63;
        float v = aspect_W[(size_t)a * E + tid];
        float ss = wave_reduce_sum(v * v);
        if (lane == 0) red[wave] = ss;
        __syncthreads();
        if (tid == 0) {
            float n = 0.f;
#pragma unroll
            for (int w = 0; w < 12; ++w) n += red[w];
            invn[a] = 1.0f / fmaxf(sqrtf(n), 1e-12f);
        }
    }
}

// ---------------- K2: qW partials (k-split 8 GEMM; sums the 2 q-halves in-stage) ----------------
__global__ __launch_bounds__(256) void qw_partial_kernel(const float* __restrict__ q,   // [2][B][E]
                                                         const float* __restrict__ W_att,
                                                         float* __restrict__ part) {   // [8][B][E]
    int b0 = blockIdx.x * 64;
    int e0 = blockIdx.y * 64;
    int kz = blockIdx.z;
    int k0 = kz * K2_KC;
    int tid = threadIdx.x;

    __shared__ __align__(16) float qs[64][K2_KC + 4];
    __shared__ __align__(16) float ws[K2_KC][64];

    int r0 = (tid >> 3) * 2;
    int c0 = (tid & 7) * 8;

    float4 a00 = make_float4(0,0,0,0), a01 = make_float4(0,0,0,0);
    float4 a10 = make_float4(0,0,0,0), a11 = make_float4(0,0,0,0);

    {
        int row = tid >> 2, ks = (tid & 3) * 24;
        const float* src0 = q + (size_t)(b0 + row) * E + k0 + ks;
        const float* src1 = src0 + (size_t)B * E;
#pragma unroll
        for (int j = 0; j < 6; ++j) {
            float4 v0 = *(const float4*)(src0 + 4 * j);
            float4 v1 = *(const float4*)(src1 + 4 * j);
            v0.x += v1.x; v0.y += v1.y; v0.z += v1.z; v0.w += v1.w;
            *(float4*)&qs[row][ks + 4 * j] = v0;
        }
    }
    for (int i = tid; i < K2_KC * 16; i += 256) {
        int row = i >> 4, e4 = (i & 15) * 4;
        *(float4*)&ws[row][e4] =
            *(const float4*)(W_att + (size_t)(k0 + row) * E + e0 + e4);
    }
    __syncthreads();
#pragma unroll 4
    for (int k = 0; k < K2_KC; ++k) {
        float qa = qs[r0][k], qb = qs[r0 + 1][k];
        float4 w0 = *(const float4*)&ws[k][c0];
        float4 w1 = *(const float4*)&ws[k][c0 + 4];
        a00.x += qa * w0.x; a00.y += qa * w0.y; a00.z += qa * w0.z; a00.w += qa * w0.w;
        a01.x += qa * w1.x; a01.y += qa * w1.y; a01.z += qa * w1.z; a01.w += qa * w1.w;
        a10.x += qb * w0.x; a10.y += qb * w0.y; a10.z += qb * w0.z; a10.w += qb * w0.w;
        a11.x += qb * w1.x; a11.y += qb * w1.y; a11.z += qb * w1.z; a11.w += qb * w1.w;
    }
    float* dst = part + ((size_t)kz * B + b0 + r0) * E + e0 + c0;
    *(float4*)dst = a00; *(float4*)(dst + 4) = a01;
    *(float4*)(dst + E) = a10; *(float4*)(dst + E + 4) = a11;
}

// ---------------- K3: single-sweep online-softmax attention, quad chains + hoisted loads ----------------
template <int USE16>
__global__ __launch_bounds__(512) void attn_ortho_kernel(const float* __restrict__ x,
                                                         const __half* __restrict__ xh,
                                                         const float* __restrict__ part,   // [8][B][E]
                                                         const float* __restrict__ b_att,
                                                         const float* __restrict__ aspect_W,
                                                         const float* __restrict__ invn,
                                                         float* __restrict__ z_s,
                                                         float* __restrict__ Gpart) {
    int bid = blockIdx.x;
    int tid = threadIdx.x, wave = tid >> 6, lane = tid & 63;
    __shared__ __align__(16) float4 qw4[E4];       // attn: qW[b]; ortho: normalized row i
    __shared__ __align__(16) float4 zw[8][E4];     // per-wave z partials (24 KB)
    __shared__ float wm[8], wl[8];
    __shared__ float red[8];

    if (bid >= B) {
        // ---- ortho block (8 waves): row i of G = Tn Tn^T - I ----
        int i = bid - B;
        float inv_i = invn[i];
        if (tid < E4) {
            float4 v = ((const float4*)aspect_W)[(size_t)i * E4 + tid];
            v.x *= inv_i; v.y *= inv_i; v.z *= inv_i; v.w *= inv_i;
            qw4[tid] = v;
        }
        __syncthreads();
        float acc = 0.f;
        for (int j = wave; j < NA; j += 8) {
            const float4* aj = (const float4*)(aspect_W + (size_t)j * E);
            float d = 0.f;
#pragma unroll
            for (int jj = 0; jj < 3; ++jj)
                d += dot4(aj[lane + 64 * jj], qw4[lane + 64 * jj]);
            d = wave_reduce_sum(d);
            if (lane == 0) {
                float g = d * invn[j] - ((i == j) ? 1.f : 0.f);
                acc += g * g;
            }
        }
        if (lane == 0) red[wave] = acc;
        __syncthreads();
        if (tid == 0) {
            float s = 0.f;
#pragma unroll
            for (int w = 0; w < 8; ++w) s += red[w];
            Gpart[i] = s;
        }
        return;
    }

    int b = bid;
    const int N4 = B * E / 4;
    // stage qW[b] = sum of 8 k-partials + b_att
    if (tid < E4) {
        const float4* p = (const float4*)part;
        size_t base = (size_t)b * E4 + tid;
        float4 r = ((const float4*)b_att)[tid];
#pragma unroll
        for (int i = 0; i < 8; ++i) {
            float4 s = p[base + (size_t)i * N4];
            r.x += s.x; r.y += s.y; r.z += s.z; r.w += s.w;
        }
        qw4[tid] = r;
    }
    __syncthreads();

    // per-lane qW fragment in registers
    float4 q0 = qw4[lane], q1 = qw4[lane + 64], q2 = qw4[lane + 128];

    float m0 = -3.4e38f, l0 = 0.f, m1 = -3.4e38f, l1 = 0.f;
    float m2 = -3.4e38f, l2 = 0.f, m3 = -3.4e38f, l3 = 0.f;
    float4 z00 = make_float4(0.f,0.f,0.f,0.f), z01 = z00, z02 = z00;
    float4 z10 = z00, z11 = z00, z12 = z00;
    float4 z20 = z00, z21 = z00, z22 = z00;
    float4 z30 = z00, z31 = z00, z32 = z00;

    const uint2*  xhb = (const uint2*)(xh + (size_t)b * S * E);
    const float4* xb  = (const float4*)(x + (size_t)b * S * E);
    int s0 = wave * 16;

    float4 a0, a1, a2;
    float m, l;

    if (USE16) {
        // ---- hoist ALL 16 rows' loads (48 uint2/lane) before any compute: max MLP ----
        uint2 raw[16][3];
#pragma unroll
        for (int r = 0; r < 16; ++r) {
            const uint2* rp = xhb + (size_t)(s0 + r) * E4;
#pragma unroll
            for (int j = 0; j < 3; ++j) raw[r][j] = rp[lane + 64 * j];
        }

#pragma unroll
        for (int i = 0; i < 16; i += 8) {
            float4 xA0 = h4_to_f4(raw[i+0][0]), xA1 = h4_to_f4(raw[i+0][1]), xA2 = h4_to_f4(raw[i+0][2]);
            float4 xB0 = h4_to_f4(raw[i+1][0]), xB1 = h4_to_f4(raw[i+1][1]), xB2 = h4_to_f4(raw[i+1][2]);
            float4 xC0 = h4_to_f4(raw[i+2][0]), xC1 = h4_to_f4(raw[i+2][1]), xC2 = h4_to_f4(raw[i+2][2]);
            float4 xD0 = h4_to_f4(raw[i+3][0]), xD1 = h4_to_f4(raw[i+3][1]), xD2 = h4_to_f4(raw[i+3][2]);
            float4 xE0 = h4_to_f4(raw[i+4][0]), xE1 = h4_to_f4(raw[i+4][1]), xE2 = h4_to_f4(raw[i+4][2]);
            float4 xF0 = h4_to_f4(raw[i+5][0]), xF1 = h4_to_f4(raw[i+5][1]), xF2 = h4_to_f4(raw[i+5][2]);
            float4 xG0 = h4_to_f4(raw[i+6][0]), xG1 = h4_to_f4(raw[i+6][1]), xG2 = h4_to_f4(raw[i+6][2]);
            float4 xH0 = h4_to_f4(raw[i+7][0]), xH1 = h4_to_f4(raw[i+7][1]), xH2 = h4_to_f4(raw[i+7][2]);

            float dA = dot4(xA0, q0) + dot4(xA1, q1) + dot4(xA2, q2);
            float dB = dot4(xB0, q0) + dot4(xB1, q1) + dot4(xB2, q2);
            float dC = dot4(xC0, q0) + dot4(xC1, q1) + dot4(xC2, q2);
            float dD = dot4(xD0, q0) + dot4(xD1, q1) + dot4(xD2, q2);
            float dE = dot4(xE0, q0) + dot4(xE1, q1) + dot4(xE2, q2);
            float dF = dot4(xF0, q0) + dot4(xF1, q1) + dot4(xF2, q2);
            float dG = dot4(xG0, q0) + dot4(xG1, q1) + dot4(xG2, q2);
            float dH = dot4(xH0, q0) + dot4(xH1, q1) + dot4(xH2, q2);
#pragma unroll
            for (int off = 32; off; off >>= 1) {
                dA += __shfl_xor(dA, off);
                dB += __shfl_xor(dB, off);
                dC += __shfl_xor(dC, off);
                dD += __shfl_xor(dD, off);
                dE += __shfl_xor(dE, off);
                dF += __shfl_xor(dF, off);
                dG += __shfl_xor(dG, off);
                dH += __shfl_xor(dH, off);
            }
            float tm0 = fmaxf(m0, fmaxf(dA, dB));
            float sc0 = __expf(m0 - tm0);
            float eA = __expf(dA - tm0), eB = __expf(dB - tm0);
            float tm1 = fmaxf(m1, fmaxf(dC, dD));
            float sc1 = __expf(m1 - tm1);
            float eC = __expf(dC - tm1), eD = __expf(dD - tm1);
            float tm2 = fmaxf(m2, fmaxf(dE, dF));
            float sc2 = __expf(m2 - tm2);
            float eE = __expf(dE - tm2), eF = __expf(dF - tm2);
            float tm3 = fmaxf(m3, fmaxf(dG, dH));
            float sc3 = __expf(m3 - tm3);
            float eG = __expf(dG - tm3), eH = __expf(dH - tm3);

            l0 = l0 * sc0 + eA + eB;
            l1 = l1 * sc1 + eC + eD;
            l2 = l2 * sc2 + eE + eF;
            l3 = l3 * sc3 + eG + eH;

            z00.x = z00.x * sc0 + eA * xA0.x + eB * xB0.x;
            z00.y = z00.y * sc0 + eA * xA0.y + eB * xB0.y;
            z00.z = z00.z * sc0 + eA * xA0.z + eB * xB0.z;
            z00.w = z00.w * sc0 + eA * xA0.w + eB * xB0.w;
            z01.x = z01.x * sc0 + eA * xA1.x + eB * xB1.x;
            z01.y = z01.y * sc0 + eA * xA1.y + eB * xB1.y;
            z01.z = z01.z * sc0 + eA * xA1.z + eB * xB1.z;
            z01.w = z01.w * sc0 + eA * xA1.w + eB * xB1.w;
            z02.x = z02.x * sc0 + eA * xA2.x + eB * xB2.x;
            z02.y = z02.y * sc0 + eA * xA2.y + eB * xB2.y;
            z02.z = z02.z * sc0 + eA * xA2.z + eB * xB2.z;
            z02.w = z02.w * sc0 + eA * xA2.w + eB * xB2.w;

            z10.x = z10.x * sc1 + eC * xC0.x + eD * xD0.x;
            z10.y = z10.y * sc1 + eC * xC0.y + eD * xD0.y;
            z10.z = z10.z * sc1 + eC * xC0.z + eD * xD0.z;
            z10.w = z10.w * sc1 + eC * xC0.w + eD * xD0.w;
            z11.x = z11.x * sc1 + eC * xC1.x + eD * xD1.x;
            z11.y = z11.y * sc1 + eC * xC1.y + eD * xD1.y;
            z11.z = z11.z * sc1 + eC * xC1.z + eD * xD1.z;
            z11.w = z11.w * sc1 + eC * xC1.w + eD * xD1.w;
            z12.x = z12.x * sc1 + eC * xC2.x + eD * xD2.x;
            z12.y = z12.y * sc1 + eC * xC2.y + eD * xD2.y;
            z12.z = z12.z * sc1 + eC * xC2.z + eD * xD2.z;
            z12.w = z12.w * sc1 + eC * xC2.w + eD * xD2.w;

            z20.x = z20.x * sc2 + eE * xE0.x + eF * xF0.x;
            z20.y = z20.y * sc2 + eE * xE0.y + eF * xF0.y;
            z20.z = z20.z * sc2 + eE * xE0.z + eF * xF0.z;
            z20.w = z20.w * sc2 + eE * xE0.w + eF * xF0.w;
            z21.x = z21.x * sc2 + eE * xE1.x + eF * xF1.x;
            z21.y = z21.y * sc2 + eE * xE1.y + eF * xF1.y;
            z21.z = z21.z * sc2 + eE * xE1.z + eF * xF1.z;
            z21.w = z21.w * sc2 + eE * xE1.w + eF * xF1.w;
            z22.x = z22.x * sc2 + eE * xE2.x + eF * xF2.x;
            z22.y = z22.y * sc2 + eE * xE2.y + eF * xF2.y;
            z22.z = z22.z * sc2 + eE * xE2.z + eF * xF2.z;
            z22.w = z22.w * sc2 + eE * xE2.w + eF * xF2.w;

            z30.x = z30.x * sc3 + eG * xG0.x + eH * xH0.x;
            z30.y = z30.y * sc3 + eG * xG0.y + eH * xH0.y;
            z30.z = z30.z * sc3 + eG * xG0.z + eH * xH0.z;
            z30.w = z30.w * sc3 + eG * xG0.w + eH * xH0.w;
            z31.x = z31.x * sc3 + eG * xG1.x + eH * xH1.x;
            z31.y = z31.y * sc3 + eG * xG1.y + eH * xH1.y;
            z31.z = z31.z * sc3 + eG * xG1.z + eH * xH1.z;
            z31.w = z31.w * sc3 + eG * xG1.w + eH * xH1.w;
            z32.x = z32.x * sc3 + eG * xG2.x + eH * xH2.x;
            z32.y = z32.y * sc3 + eG * xG2.y + eH * xH2.y;
            z32.z = z32.z * sc3 + eG * xG2.z + eH * xH2.z;
            z32.w = z32.w * sc3 + eG * xG2.w + eH * xH2.w;

            m0 = tm0; m1 = tm1; m2 = tm2; m3 = tm3;
        }
    } else {
        // f32 fallback (two-at-a-time, dual chain folded into chain 0/1 only)
#pragma unroll
        for (int i = 0; i < 16; i += 2) {
            const float4* rA = xb + (size_t)(s0 + i) * E4;
            const float4* rB = rA + E4;
            float4 xA0 = rA[lane], xA1 = rA[lane + 64], xA2 = rA[lane + 128];
            float4 xB0 = rB[lane], xB1 = rB[lane + 64], xB2 = rB[lane + 128];
            float dA = dot4(xA0, q0) + dot4(xA1, q1) + dot4(xA2, q2);
            float dB = dot4(xB0, q0) + dot4(xB1, q1) + dot4(xB2, q2);
#pragma unroll
            for (int off = 32; off; off >>= 1) {
                dA += __shfl_xor(dA, off);
                dB += __shfl_xor(dB, off);
            }
            float tm0 = fmaxf(m0, fmaxf(dA, dB));
            float sc0 = __expf(m0 - tm0);
            float eA = __expf(dA - tm0), eB = __expf(dB - tm0);
            l0 = l0 * sc0 + eA + eB;
            z00.x = z00.x * sc0 + eA * xA0.x + eB * xB0.x;
            z00.y = z00.y * sc0 + eA * xA0.y + eB * xB0.y;
            z00.z = z00.z * sc0 + eA * xA0.z + eB * xB0.z;
            z00.w = z00.w * sc0 + eA * xA0.w + eB * xB0.w;
            z01.x = z01.x * sc0 + eA * xA1.x + eB * xB1.x;
            z01.y = z01.y * sc0 + eA * xA1.y + eB * xB1.y;
            z01.z = z01.z * sc0 + eA * xA1.z + eB * xB1.z;
            z01.w = z01.w * sc0 + eA * xA1.w + eB * xB1.w;
            z02.x = z02.x * sc0 + eA * xA2.x + eB * xB2.x;
            z02.y = z02.y * sc0 + eA * xA2.y + eB * xB2.y;
            z02.z = z02.z * sc0 + eA * xA2.z + eB * xB2.z;
            z02.w = z02.w * sc0 + eA * xA2.w + eB * xB2.w;
            m0 = tm0;
        }
        m1 = -3.4e38f; l1 = 0.f; m2 = -3.4e38f; l2 = 0.f; m3 = -3.4e38f; l3 = 0.f;
    }

    // pairwise exact merges: (0,1) -> A, (2,3) -> B, then (A,B)
    {
        float mA = fmaxf(m0, m1);
        float fA0 = __expf(m0 - mA), fA1 = __expf(m1 - mA);
        float lA = l0 * fA0 + l1 * fA1;
        float4 A0, A1, A2;
        A0.x = z00.x * fA0 + z10.x * fA1; A0.y = z00.y * fA0 + z10.y * fA1;
        A0.z = z00.z * fA0 + z10.z * fA1; A0.w = z00.w * fA0 + z10.w * fA1;
        A1.x = z01.x * fA0 + z11.x * fA1; A1.y = z01.y * fA0 + z11.y * fA1;
        A1.z = z01.z * fA0 + z11.z * fA1; A1.w = z01.w * fA0 + z11.w * fA1;
        A2.x = z02.x * fA0 + z12.x * fA1; A2.y = z02.y * fA0 + z12.y * fA1;
        A2.z = z02.z * fA0 + z12.z * fA1; A2.w = z02.w * fA0 + z12.w * fA1;

        float mB = fmaxf(m2, m3);
        float fB0 = __expf(m2 - mB), fB1 = __expf(m3 - mB);
        float lB = l2 * fB0 + l3 * fB1;
        float4 B0, B1, B2;
        B0.x = z20.x * fB0 + z30.x * fB1; B0.y = z20.y * fB0 + z30.y * fB1;
        B0.z = z20.z * fB0 + z30.z * fB1; B0.w = z20.w * fB0 + z30.w * fB1;
        B1.x = z21.x * fB0 + z31.x * fB1; B1.y = z21.y * fB0 + z31.y * fB1;
        B1.z = z21.z * fB0 + z31.z * fB1; B1.w = z21.w * fB0 + z31.w * fB1;
        B2.x = z22.x * fB0 + z32.x * fB1; B2.y = z22.y * fB0 + z32.y * fB1;
        B2.z = z22.z * fB0 + z32.z * fB1; B2.w = z22.w * fB0 + z32.w * fB1;

        m = fmaxf(mA, mB);
        float f0 = __expf(mA - m), f1 = __expf(mB - m);
        l = lA * f0 + lB * f1;
        a0.x = A0.x * f0 + B0.x * f1; a0.y = A0.y * f0 + B0.y * f1;
        a0.z = A0.z * f0 + B0.z * f1; a0.w = A0.w * f0 + B0.w * f1;
        a1.x = A1.x * f0 + B1.x * f1; a1.y = A1.y * f0 + B1.y * f1;
        a1.z = A1.z * f0 + B1.z * f1; a1.w = A1.w * f0 + B1.w * f1;
        a2.x = A2.x * f0 + B2.x * f1; a2.y = A2.y * f0 + B2.y * f1;
        a2.z = A2.z * f0 + B2.z * f1; a2.w = A2.w * f0 + B2.w * f1;
    }

    // per-wave partials to LDS
    zw[wave][lane] = a0;
    zw[wave][lane + 64] = a1;
    zw[wave][lane + 128] = a2;
    if (lane == 0) { wm[wave] = m; wl[wave] = l; }
    __syncthreads();

    // combine 8 waves with rescale (threads 0..191)
    if (tid < E4) {
        float M = wm[0];
#pragma unroll
        for (int w = 1; w < 8; ++w) M = fmaxf(M, wm[w]);
        float L = 0.f;
        float4 z = make_float4(0.f, 0.f, 0.f, 0.f);
#pragma unroll
        for (int w = 0; w < 8; ++w) {
            float f = __expf(wm[w] - M);
            float4 a = zw[w][tid];
            z.x += f * a.x; z.y += f * a.y; z.z += f * a.z; z.w += f * a.w;
            L += f * wl[w];
        }
        float invL = 1.0f / L;
        z.x *= invL; z.y *= invL; z.z *= invL; z.w *= invL;
        ((float4*)z_s)[(size_t)b * E4 + tid] = z;
    }
}

// ---------------- K4: composition + reconstruction + margin (768 thr) ----------------
__global__ __launch_bounds__(768) void recon_margin_kernel(const float* __restrict__ z_s,
                                                           const float* __restrict__ WredT,
                                                           const float* __restrict__ b_red,
                                                           const float* __restrict__ aspect_W,
                                                           const int* __restrict__ neg_idx,
                                                           float* __restrict__ recon,
                                                           float* __restrict__ mpart) {
    int b = blockIdx.x;
    int tid = threadIdx.x, wave = tid >> 6, lane = tid & 63;
    __shared__ __align__(16) float4 z4[E4];
    __shared__ float comp[NA];
    __shared__ __align__(16) float r_sh[E];
    __shared__ float red[12];
    __shared__ float dots[12];

    if (tid < E4) z4[tid] = ((const float4*)(z_s + (size_t)b * E))[tid];
    __syncthreads();

    for (int a = wave; a < NA; a += 12) {
        const float4* wr = (const float4*)(WredT + (size_t)a * E);
        float d = 0.f;
#pragma unroll
        for (int j = 0; j < 3; ++j)
            d += dot4(wr[lane + 64 * j], z4[lane + 64 * j]);
        d = wave_reduce_sum(d);
        if (lane == 0) comp[a] = d + b_red[a];
    }
    __syncthreads();

    if (wave == 0) {
        float v = (lane < NA) ? comp[lane] : -3.4e38f;
        float m = wave_reduce_max(v);
        m = __shfl(m, 0);
        float e = (lane < NA) ? expf(v - m) : 0.f;
        float ssum = wave_reduce_sum(e);
        ssum = __shfl(ssum, 0);
        if (lane < NA) comp[lane] = e / ssum;
    }
    __syncthreads();

    float r = 0.f;
    for (int a = 0; a < NA; ++a)
        r += comp[a] * aspect_W[(size_t)a * E + tid];
    recon[(size_t)b * E + tid] = r;
    r_sh[tid] = r;
    float sq = wave_reduce_sum(r * r);
    if (lane == 0) red[wave] = sq;
    __syncthreads();
    float tot = 0.f;
#pragma unroll
    for (int w = 0; w < 12; ++w) tot += red[w];
    float inv = 1.0f / fmaxf(sqrtf(tot), 1e-12f);

    if (wave <= NNEG) {
        int row = (wave == 0) ? b : neg_idx[b * NNEG + (wave - 1)];
        const float4* zr = (const float4*)(z_s + (size_t)row * E);
        const float4* rr = (const float4*)r_sh;
        float acc = 0.f;
#pragma unroll
        for (int j = 0; j < 3; ++j)
            acc += dot4(zr[lane + 64 * j], rr[lane + 64 * j]);
        acc = wave_reduce_sum(acc);
        if (lane == 0) dots[wave] = acc;
    }
    __syncthreads();
    if (tid == 0) {
        float pos = dots[0] * inv;
        float ssum = 0.f;
        for (int n = 1; n <= NNEG; ++n)
            ssum += fmaxf(1.f - pos + dots[n] * inv, 0.f);
        mpart[b] = ssum;
    }
}

// ---------------- K5: final scalar loss ----------------
__global__ __launch_bounds__(256) void loss_kernel(const float* __restrict__ Gpart,
                                                   const float* __restrict__ mpart,
                                                   float* __restrict__ loss_out) {
    int tid = threadIdx.x, wave = tid >> 6, lane = tid & 63;
    __shared__ float ra[4], rb[4];
    float fr = (tid < NA) ? Gpart[tid] : 0.f;
    fr = wave_reduce_sum(fr);
    if (lane == 0) ra[wave] = fr;
    float mp = mpart[tid];
    mp = wave_reduce_sum(mp);
    if (lane == 0) rb[wave] = mp;
    __syncthreads();
    if (tid == 0) {
        float frob = sqrtf(ra[0] + ra[1] + ra[2] + ra[3]);
        float msum = rb[0] + rb[1] + rb[2] + rb[3];
        loss_out[0] = frob + msum * (1.0f / (float)(B * NNEG));
    }
}

extern "C" void kernel_launch(void* const* d_in, const int* in_sizes, int n_in,
                              void* d_out, int out_size, void* d_ws, size_t ws_size,
                              hipStream_t stream) {
    const float* x        = (const float*)d_in[0];
    const float* W_att    = (const float*)d_in[1];
    const float* b_att    = (const float*)d_in[2];
    const float* W_red    = (const float*)d_in[3];
    const float* b_red    = (const float*)d_in[4];
    const float* aspect_W = (const float*)d_in[5];
    const int*   neg_idx  = (const int*)d_in[6];

    float* out   = (float*)d_out;
    float* z_s   = out;                       // [B,E]
    float* recon = out + (size_t)B * E;       // [B,E]
    float* loss  = out + (size_t)2 * B * E;   // [1]

    float* ws    = (float*)d_ws;
    float* q     = ws;                        // 2*B*E
    float* part2 = q + (size_t)2 * B * E;     // 8*B*E
    float* WredT = part2 + (size_t)8 * B * E; // NA*E
    float* invn  = WredT + (size_t)NA * E;    // 32
    float* Gpart = invn + 32;                 // 32
    float* mpart = Gpart + 32;                // B
    float* endf  = mpart + B;

    size_t base_floats = (size_t)(endf - ws);
    size_t need = base_floats * sizeof(float) + (size_t)B * S * E * sizeof(__half);
    bool use16 = (ws_size >= need);
    __half* xh = (__half*)(ws + base_floats);

    if (use16) {
        mean_prep_kernel<1><<<2 * B + NA, 768, 0, stream>>>(x, W_red, aspect_W, q, WredT, invn, xh);
        qw_partial_kernel<<<dim3(4, 12, 8), 256, 0, stream>>>(q, W_att, part2);
        attn_ortho_kernel<1><<<B + NA, 512, 0, stream>>>(x, xh, part2, b_att, aspect_W, invn, z_s, Gpart);
    } else {
        mean_prep_kernel<0><<<2 * B + NA, 768, 0, stream>>>(x, W_red, aspect_W, q, WredT, invn, xh);
        qw_partial_kernel<<<dim3(4, 12, 8), 256, 0, stream>>>(q, W_att, part2);
        attn_ortho_kernel<0><<<B + NA, 512, 0, stream>>>(x, xh, part2, b_att, aspect_W, invn, z_s, Gpart);
    }
    recon_margin_kernel<<<B, 768, 0, stream>>>(z_s, WredT, b_red, aspect_W, neg_idx, recon, mpart);
    loss_kernel<<<1, 256, 0, stream>>>(Gpart, mpart, loss);
}

// Round 18
// 63.187 us; speedup vs baseline: 1.0626x; 1.0099x over previous
//
#include <hip/hip_runtime.h>
#include <hip/hip_bf16.h>
#include <hip/hip_fp16.h>
#include <math.h>

#define B 256
#define S 128
#define E 768
#define E4 192      // E/4 (float4 per row)
#define NA 30
#define NNEG 10

#define K2_KC 96    // k-chunk per block; ksplit = 8

__device__ __forceinline__ float dot4(float4 a, float4 b) {
    return a.x * b.x + a.y * b.y + a.z * b.z + a.w * b.w;
}
__device__ __forceinline__ float wave_reduce_sum(float v) {
#pragma unroll
    for (int off = 32; off; off >>= 1) v += __shfl_down(v, off);
    return v;   // valid on lane 0
}
__device__ __forceinline__ float wave_reduce_max(float v) {
#pragma unroll
    for (int off = 32; off; off >>= 1) v = fmaxf(v, __shfl_down(v, off));
    return v;   // valid on lane 0
}
__device__ __forceinline__ float4 h4_to_f4(uint2 p) {
    __half2* ph = (__half2*)&p;
    float2 f0 = __half22float2(ph[0]);
    float2 f1 = __half22float2(ph[1]);
    return make_float4(f0.x, f0.y, f1.x, f1.y);
}

// ---------------- K1: q-partials (2/b) + fp16 x-copy + 30 self-contained ortho blocks ----------------
template <int USE16>
__global__ __launch_bounds__(768) void mean_prep_kernel(const float* __restrict__ x,
                                                        const float* __restrict__ W_red,
                                                        const float* __restrict__ aspect_W,
                                                        float* __restrict__ q,      // [2][B][E]
                                                        float* __restrict__ WredT,
                                                        float* __restrict__ Gpart,
                                                        __half* __restrict__ xh) {
    int bid = blockIdx.x;
    int tid = threadIdx.x;
    int wave = tid >> 6, lane = tid & 63;
    __shared__ __align__(16) float4 part[4][E4];
    __shared__ float red[12];
    __shared__ float nrm[32];

    if (bid < 2 * B) {
        int b = bid >> 1, half = bid & 1;
        int c = tid % E4;     // float4 column
        int g = tid / E4;     // 0..3 (s-subgroup)
        const float4* xb = (const float4*)(x + (size_t)b * S * E);
        uint2* xhb = (uint2*)(xh + (size_t)b * S * E);
        int s0 = half * 64 + g * 16;
        float4 acc = make_float4(0.f, 0.f, 0.f, 0.f);
#pragma unroll 4
        for (int s = s0; s < s0 + 16; ++s) {
            float4 v = xb[(size_t)s * E4 + c];
            acc.x += v.x; acc.y += v.y; acc.z += v.z; acc.w += v.w;
            if (USE16) {
                __half2 h01 = __floats2half2_rn(v.x, v.y);
                __half2 h23 = __floats2half2_rn(v.z, v.w);
                uint2 pk;
                pk.x = *(unsigned int*)&h01;
                pk.y = *(unsigned int*)&h23;
                xhb[(size_t)s * E4 + c] = pk;
            }
        }
        part[g][c] = acc;
        __syncthreads();
        if (tid < E4) {
            float4 a0 = part[0][c], a1 = part[1][c], a2 = part[2][c], a3 = part[3][c];
            const float inv = 1.0f / (float)S;      // halves sum to the mean
            float4 r;
            r.x = (a0.x + a1.x + a2.x + a3.x) * inv;
            r.y = (a0.y + a1.y + a2.y + a3.y) * inv;
            r.z = (a0.z + a1.z + a2.z + a3.z) * inv;
            r.w = (a0.w + a1.w + a2.w + a3.w) * inv;
            ((float4*)q)[((size_t)half * B + b) * E4 + c] = r;
        }
    } else {
        // ---- self-contained ortho block i: transpose column + row i of G = Tn Tn^T - I ----
        int i = bid - 2 * B;                       // 0..29
        WredT[(size_t)i * E + tid] = W_red[(size_t)tid * NA + i];

        // all 30 inverse norms (rows L2-hot, trivial)
        for (int j = wave; j < NA; j += 12) {
            const float4* aj = (const float4*)(aspect_W + (size_t)j * E);
            float ss = 0.f;
#pragma unroll
            for (int jj = 0; jj < 3; ++jj) {
                float4 v = aj[lane + 64 * jj];
                ss += dot4(v, v);
            }
            ss = wave_reduce_sum(ss);
            if (lane == 0) nrm[j] = 1.0f / fmaxf(sqrtf(ss), 1e-12f);
        }
        __syncthreads();

        // stage normalized row i in LDS (reuse part[0])
        if (tid < E4) {
            float4 v = ((const float4*)aspect_W)[(size_t)i * E4 + tid];
            float s = nrm[i];
            v.x *= s; v.y *= s; v.z *= s; v.w *= s;
            part[0][tid] = v;
        }
        __syncthreads();

        float acc = 0.f;
        for (int j = wave; j < NA; j += 12) {
            const float4* aj = (const float4*)(aspect_W + (size_t)j * E);
            float d = 0.f;
#pragma unroll
            for (int jj = 0; jj < 3; ++jj)
                d += dot4(aj[lane + 64 * jj], part[0][lane + 64 * jj]);
            d = wave_reduce_sum(d);
            if (lane == 0) {
                float g = d * nrm[j] - ((i == j) ? 1.f : 0.f);
                acc += g * g;
            }
        }
        if (lane == 0) red[wave] = acc;
        __syncthreads();
        if (tid == 0) {
            float s = 0.f;
#pragma unroll
            for (int w = 0; w < 12; ++w) s += red[w];
            Gpart[i] = s;
        }
    }
}

// ---------------- K2: qW partials (k-split 8 GEMM; sums the 2 q-halves in-stage) ----------------
__global__ __launch_bounds__(256) void qw_partial_kernel(const float* __restrict__ q,   // [2][B][E]
                                                         const float* __restrict__ W_att,
                                                         float* __restrict__ part) {   // [8][B][E]
    int b0 = blockIdx.x * 64;
    int e0 = blockIdx.y * 64;
    int kz = blockIdx.z;
    int k0 = kz * K2_KC;
    int tid = threadIdx.x;

    __shared__ __align__(16) float qs[64][K2_KC + 4];
    __shared__ __align__(16) float ws[K2_KC][64];

    int r0 = (tid >> 3) * 2;
    int c0 = (tid & 7) * 8;

    float4 a00 = make_float4(0,0,0,0), a01 = make_float4(0,0,0,0);
    float4 a10 = make_float4(0,0,0,0), a11 = make_float4(0,0,0,0);

    {
        int row = tid >> 2, ks = (tid & 3) * 24;
        const float* src0 = q + (size_t)(b0 + row) * E + k0 + ks;
        const float* src1 = src0 + (size_t)B * E;
#pragma unroll
        for (int j = 0; j < 6; ++j) {
            float4 v0 = *(const float4*)(src0 + 4 * j);
            float4 v1 = *(const float4*)(src1 + 4 * j);
            v0.x += v1.x; v0.y += v1.y; v0.z += v1.z; v0.w += v1.w;
            *(float4*)&qs[row][ks + 4 * j] = v0;
        }
    }
    for (int i = tid; i < K2_KC * 16; i += 256) {
        int row = i >> 4, e4 = (i & 15) * 4;
        *(float4*)&ws[row][e4] =
            *(const float4*)(W_att + (size_t)(k0 + row) * E + e0 + e4);
    }
    __syncthreads();
#pragma unroll 4
    for (int k = 0; k < K2_KC; ++k) {
        float qa = qs[r0][k], qb = qs[r0 + 1][k];
        float4 w0 = *(const float4*)&ws[k][c0];
        float4 w1 = *(const float4*)&ws[k][c0 + 4];
        a00.x += qa * w0.x; a00.y += qa * w0.y; a00.z += qa * w0.z; a00.w += qa * w0.w;
        a01.x += qa * w1.x; a01.y += qa * w1.y; a01.z += qa * w1.z; a01.w += qa * w1.w;
        a10.x += qb * w0.x; a10.y += qb * w0.y; a10.z += qb * w0.z; a10.w += qb * w0.w;
        a11.x += qb * w1.x; a11.y += qb * w1.y; a11.z += qb * w1.z; a11.w += qb * w1.w;
    }
    float* dst = part + ((size_t)kz * B + b0 + r0) * E + e0 + c0;
    *(float4*)dst = a00; *(float4*)(dst + 4) = a01;
    *(float4*)(dst + E) = a10; *(float4*)(dst + E + 4) = a11;
}

// ---------------- K3: single-sweep online-softmax attention (grid exactly B) ----------------
template <int USE16>
__global__ __launch_bounds__(512) void attn_kernel(const float* __restrict__ x,
                                                   const __half* __restrict__ xh,
                                                   const float* __restrict__ part,   // [8][B][E]
                                                   const float* __restrict__ b_att,
                                                   float* __restrict__ z_s) {
    int b = blockIdx.x;
    int tid = threadIdx.x, wave = tid >> 6, lane = tid & 63;
    __shared__ __align__(16) float4 qw4[E4];
    __shared__ __align__(16) float4 zw[8][E4];
    __shared__ float wm[8], wl[8];

    const int N4 = B * E / 4;
    if (tid < E4) {
        const float4* p = (const float4*)part;
        size_t base = (size_t)b * E4 + tid;
        float4 r = ((const float4*)b_att)[tid];
#pragma unroll
        for (int i = 0; i < 8; ++i) {
            float4 s = p[base + (size_t)i * N4];
            r.x += s.x; r.y += s.y; r.z += s.z; r.w += s.w;
        }
        qw4[tid] = r;
    }
    __syncthreads();

    float4 q0 = qw4[lane], q1 = qw4[lane + 64], q2 = qw4[lane + 128];

    float m0 = -3.4e38f, l0 = 0.f, m1 = -3.4e38f, l1 = 0.f;
    float m2 = -3.4e38f, l2 = 0.f, m3 = -3.4e38f, l3 = 0.f;
    float4 z00 = make_float4(0.f,0.f,0.f,0.f), z01 = z00, z02 = z00;
    float4 z10 = z00, z11 = z00, z12 = z00;
    float4 z20 = z00, z21 = z00, z22 = z00;
    float4 z30 = z00, z31 = z00, z32 = z00;

    const uint2*  xhb = (const uint2*)(xh + (size_t)b * S * E);
    const float4* xb  = (const float4*)(x + (size_t)b * S * E);
    int s0 = wave * 16;

    float4 a0, a1, a2;
    float m, l;

    if (USE16) {
        uint2 raw[16][3];
#pragma unroll
        for (int r = 0; r < 16; ++r) {
            const uint2* rp = xhb + (size_t)(s0 + r) * E4;
#pragma unroll
            for (int j = 0; j < 3; ++j) raw[r][j] = rp[lane + 64 * j];
        }

#pragma unroll
        for (int i = 0; i < 16; i += 8) {
            float4 xA0 = h4_to_f4(raw[i+0][0]), xA1 = h4_to_f4(raw[i+0][1]), xA2 = h4_to_f4(raw[i+0][2]);
            float4 xB0 = h4_to_f4(raw[i+1][0]), xB1 = h4_to_f4(raw[i+1][1]), xB2 = h4_to_f4(raw[i+1][2]);
            float4 xC0 = h4_to_f4(raw[i+2][0]), xC1 = h4_to_f4(raw[i+2][1]), xC2 = h4_to_f4(raw[i+2][2]);
            float4 xD0 = h4_to_f4(raw[i+3][0]), xD1 = h4_to_f4(raw[i+3][1]), xD2 = h4_to_f4(raw[i+3][2]);
            float4 xE0 = h4_to_f4(raw[i+4][0]), xE1 = h4_to_f4(raw[i+4][1]), xE2 = h4_to_f4(raw[i+4][2]);
            float4 xF0 = h4_to_f4(raw[i+5][0]), xF1 = h4_to_f4(raw[i+5][1]), xF2 = h4_to_f4(raw[i+5][2]);
            float4 xG0 = h4_to_f4(raw[i+6][0]), xG1 = h4_to_f4(raw[i+6][1]), xG2 = h4_to_f4(raw[i+6][2]);
            float4 xH0 = h4_to_f4(raw[i+7][0]), xH1 = h4_to_f4(raw[i+7][1]), xH2 = h4_to_f4(raw[i+7][2]);

            float dA = dot4(xA0, q0) + dot4(xA1, q1) + dot4(xA2, q2);
            float dB = dot4(xB0, q0) + dot4(xB1, q1) + dot4(xB2, q2);
            float dC = dot4(xC0, q0) + dot4(xC1, q1) + dot4(xC2, q2);
            float dD = dot4(xD0, q0) + dot4(xD1, q1) + dot4(xD2, q2);
            float dE = dot4(xE0, q0) + dot4(xE1, q1) + dot4(xE2, q2);
            float dF = dot4(xF0, q0) + dot4(xF1, q1) + dot4(xF2, q2);
            float dG = dot4(xG0, q0) + dot4(xG1, q1) + dot4(xG2, q2);
            float dH = dot4(xH0, q0) + dot4(xH1, q1) + dot4(xH2, q2);
#pragma unroll
            for (int off = 32; off; off >>= 1) {
                dA += __shfl_xor(dA, off);
                dB += __shfl_xor(dB, off);
                dC += __shfl_xor(dC, off);
                dD += __shfl_xor(dD, off);
                dE += __shfl_xor(dE, off);
                dF += __shfl_xor(dF, off);
                dG += __shfl_xor(dG, off);
                dH += __shfl_xor(dH, off);
            }
            float tm0 = fmaxf(m0, fmaxf(dA, dB));
            float sc0 = __expf(m0 - tm0);
            float eA = __expf(dA - tm0), eB = __expf(dB - tm0);
            float tm1 = fmaxf(m1, fmaxf(dC, dD));
            float sc1 = __expf(m1 - tm1);
            float eC = __expf(dC - tm1), eD = __expf(dD - tm1);
            float tm2 = fmaxf(m2, fmaxf(dE, dF));
            float sc2 = __expf(m2 - tm2);
            float eE = __expf(dE - tm2), eF = __expf(dF - tm2);
            float tm3 = fmaxf(m3, fmaxf(dG, dH));
            float sc3 = __expf(m3 - tm3);
            float eG = __expf(dG - tm3), eH = __expf(dH - tm3);

            l0 = l0 * sc0 + eA + eB;
            l1 = l1 * sc1 + eC + eD;
            l2 = l2 * sc2 + eE + eF;
            l3 = l3 * sc3 + eG + eH;

            z00.x = z00.x * sc0 + eA * xA0.x + eB * xB0.x;
            z00.y = z00.y * sc0 + eA * xA0.y + eB * xB0.y;
            z00.z = z00.z * sc0 + eA * xA0.z + eB * xB0.z;
            z00.w = z00.w * sc0 + eA * xA0.w + eB * xB0.w;
            z01.x = z01.x * sc0 + eA * xA1.x + eB * xB1.x;
            z01.y = z01.y * sc0 + eA * xA1.y + eB * xB1.y;
            z01.z = z01.z * sc0 + eA * xA1.z + eB * xB1.z;
            z01.w = z01.w * sc0 + eA * xA1.w + eB * xB1.w;
            z02.x = z02.x * sc0 + eA * xA2.x + eB * xB2.x;
            z02.y = z02.y * sc0 + eA * xA2.y + eB * xB2.y;
            z02.z = z02.z * sc0 + eA * xA2.z + eB * xB2.z;
            z02.w = z02.w * sc0 + eA * xA2.w + eB * xB2.w;

            z10.x = z10.x * sc1 + eC * xC0.x + eD * xD0.x;
            z10.y = z10.y * sc1 + eC * xC0.y + eD * xD0.y;
            z10.z = z10.z * sc1 + eC * xC0.z + eD * xD0.z;
            z10.w = z10.w * sc1 + eC * xC0.w + eD * xD0.w;
            z11.x = z11.x * sc1 + eC * xC1.x + eD * xD1.x;
            z11.y = z11.y * sc1 + eC * xC1.y + eD * xD1.y;
            z11.z = z11.z * sc1 + eC * xC1.z + eD * xD1.z;
            z11.w = z11.w * sc1 + eC * xC1.w + eD * xD1.w;
            z12.x = z12.x * sc1 + eC * xC2.x + eD * xD2.x;
            z12.y = z12.y * sc1 + eC * xC2.y + eD * xD2.y;
            z12.z = z12.z * sc1 + eC * xC2.z + eD * xD2.z;
            z12.w = z12.w * sc1 + eC * xC2.w + eD * xD2.w;

            z20.x = z20.x * sc2 + eE * xE0.x + eF * xF0.x;
            z20.y = z20.y * sc2 + eE * xE0.y + eF * xF0.y;
            z20.z = z20.z * sc2 + eE * xE0.z + eF * xF0.z;
            z20.w = z20.w * sc2 + eE * xE0.w + eF * xF0.w;
            z21.x = z21.x * sc2 + eE * xE1.x + eF * xF1.x;
            z21.y = z21.y * sc2 + eE * xE1.y + eF * xF1.y;
            z21.z = z21.z * sc2 + eE * xE1.z + eF * xF1.z;
            z21.w = z21.w * sc2 + eE * xE1.w + eF * xF1.w;
            z22.x = z22.x * sc2 + eE * xE2.x + eF * xF2.x;
            z22.y = z22.y * sc2 + eE * xE2.y + eF * xF2.y;
            z22.z = z22.z * sc2 + eE * xE2.z + eF * xF2.z;
            z22.w = z22.w * sc2 + eE * xE2.w + eF * xF2.w;

            z30.x = z30.x * sc3 + eG * xG0.x + eH * xH0.x;
            z30.y = z30.y * sc3 + eG * xG0.y + eH * xH0.y;
            z30.z = z30.z * sc3 + eG * xG0.z + eH * xH0.z;
            z30.w = z30.w * sc3 + eG * xG0.w + eH * xH0.w;
            z31.x = z31.x * sc3 + eG * xG1.x + eH * xH1.x;
            z31.y = z31.y * sc3 + eG * xG1.y + eH * xH1.y;
            z31.z = z31.z * sc3 + eG * xG1.z + eH * xH1.z;
            z31.w = z31.w * sc3 + eG * xG1.w + eH * xH1.w;
            z32.x = z32.x * sc3 + eG * xG2.x + eH * xH2.x;
            z32.y = z32.y * sc3 + eG * xG2.y + eH * xH2.y;
            z32.z = z32.z * sc3 + eG * xG2.z + eH * xH2.z;
            z32.w = z32.w * sc3 + eG * xG2.w + eH * xH2.w;

            m0 = tm0; m1 = tm1; m2 = tm2; m3 = tm3;
        }
    } else {
#pragma unroll
        for (int i = 0; i < 16; i += 2) {
            const float4* rA = xb + (size_t)(s0 + i) * E4;
            const float4* rB = rA + E4;
            float4 xA0 = rA[lane], xA1 = rA[lane + 64], xA2 = rA[lane + 128];
            float4 xB0 = rB[lane], xB1 = rB[lane + 64], xB2 = rB[lane + 128];
            float dA = dot4(xA0, q0) + dot4(xA1, q1) + dot4(xA2, q2);
            float dB = dot4(xB0, q0) + dot4(xB1, q1) + dot4(xB2, q2);
#pragma unroll
            for (int off = 32; off; off >>= 1) {
                dA += __shfl_xor(dA, off);
                dB += __shfl_xor(dB, off);
            }
            float tm0 = fmaxf(m0, fmaxf(dA, dB));
            float sc0 = __expf(m0 - tm0);
            float eA = __expf(dA - tm0), eB = __expf(dB - tm0);
            l0 = l0 * sc0 + eA + eB;
            z00.x = z00.x * sc0 + eA * xA0.x + eB * xB0.x;
            z00.y = z00.y * sc0 + eA * xA0.y + eB * xB0.y;
            z00.z = z00.z * sc0 + eA * xA0.z + eB * xB0.z;
            z00.w = z00.w * sc0 + eA * xA0.w + eB * xB0.w;
            z01.x = z01.x * sc0 + eA * xA1.x + eB * xB1.x;
            z01.y = z01.y * sc0 + eA * xA1.y + eB * xB1.y;
            z01.z = z01.z * sc0 + eA * xA1.z + eB * xB1.z;
            z01.w = z01.w * sc0 + eA * xA1.w + eB * xB1.w;
            z02.x = z02.x * sc0 + eA * xA2.x + eB * xB2.x;
            z02.y = z02.y * sc0 + eA * xA2.y + eB * xB2.y;
            z02.z = z02.z * sc0 + eA * xA2.z + eB * xB2.z;
            z02.w = z02.w * sc0 + eA * xA2.w + eB * xB2.w;
            m0 = tm0;
        }
        m1 = -3.4e38f; l1 = 0.f; m2 = -3.4e38f; l2 = 0.f; m3 = -3.4e38f; l3 = 0.f;
    }

    // pairwise exact merges
    {
        float mA = fmaxf(m0, m1);
        float fA0 = __expf(m0 - mA), fA1 = __expf(m1 - mA);
        float lA = l0 * fA0 + l1 * fA1;
        float4 A0, A1, A2;
        A0.x = z00.x * fA0 + z10.x * fA1; A0.y = z00.y * fA0 + z10.y * fA1;
        A0.z = z00.z * fA0 + z10.z * fA1; A0.w = z00.w * fA0 + z10.w * fA1;
        A1.x = z01.x * fA0 + z11.x * fA1; A1.y = z01.y * fA0 + z11.y * fA1;
        A1.z = z01.z * fA0 + z11.z * fA1; A1.w = z01.w * fA0 + z11.w * fA1;
        A2.x = z02.x * fA0 + z12.x * fA1; A2.y = z02.y * fA0 + z12.y * fA1;
        A2.z = z02.z * fA0 + z12.z * fA1; A2.w = z02.w * fA0 + z12.w * fA1;

        float mB = fmaxf(m2, m3);
        float fB0 = __expf(m2 - mB), fB1 = __expf(m3 - mB);
        float lB = l2 * fB0 + l3 * fB1;
        float4 B0, B1, B2;
        B0.x = z20.x * fB0 + z30.x * fB1; B0.y = z20.y * fB0 + z30.y * fB1;
        B0.z = z20.z * fB0 + z30.z * fB1; B0.w = z20.w * fB0 + z30.w * fB1;
        B1.x = z21.x * fB0 + z31.x * fB1; B1.y = z21.y * fB0 + z31.y * fB1;
        B1.z = z21.z * fB0 + z31.z * fB1; B1.w = z21.w * fB0 + z31.w * fB1;
        B2.x = z22.x * fB0 + z32.x * fB1; B2.y = z22.y * fB0 + z32.y * fB1;
        B2.z = z22.z * fB0 + z32.z * fB1; B2.w = z22.w * fB0 + z32.w * fB1;

        m = fmaxf(mA, mB);
        float f0 = __expf(mA - m), f1 = __expf(mB - m);
        l = lA * f0 + lB * f1;
        a0.x = A0.x * f0 + B0.x * f1; a0.y = A0.y * f0 + B0.y * f1;
        a0.z = A0.z * f0 + B0.z * f1; a0.w = A0.w * f0 + B0.w * f1;
        a1.x = A1.x * f0 + B1.x * f1; a1.y = A1.y * f0 + B1.y * f1;
        a1.z = A1.z * f0 + B1.z * f1; a1.w = A1.w * f0 + B1.w * f1;
        a2.x = A2.x * f0 + B2.x * f1; a2.y = A2.y * f0 + B2.y * f1;
        a2.z = A2.z * f0 + B2.z * f1; a2.w = A2.w * f0 + B2.w * f1;
    }

    zw[wave][lane] = a0;
    zw[wave][lane + 64] = a1;
    zw[wave][lane + 128] = a2;
    if (lane == 0) { wm[wave] = m; wl[wave] = l; }
    __syncthreads();

    if (tid < E4) {
        float M = wm[0];
#pragma unroll
        for (int w = 1; w < 8; ++w) M = fmaxf(M, wm[w]);
        float L = 0.f;
        float4 z = make_float4(0.f, 0.f, 0.f, 0.f);
#pragma unroll
        for (int w = 0; w < 8; ++w) {
            float f = __expf(wm[w] - M);
            float4 a = zw[w][tid];
            z.x += f * a.x; z.y += f * a.y; z.z += f * a.z; z.w += f * a.w;
            L += f * wl[w];
        }
        float invL = 1.0f / L;
        z.x *= invL; z.y *= invL; z.z *= invL; z.w *= invL;
        ((float4*)z_s)[(size_t)b * E4 + tid] = z;
    }
}

// ---------------- K4: composition + reconstruction + margin (768 thr) ----------------
__global__ __launch_bounds__(768) void recon_margin_kernel(const float* __restrict__ z_s,
                                                           const float* __restrict__ WredT,
                                                           const float* __restrict__ b_red,
                                                           const float* __restrict__ aspect_W,
                                                           const int* __restrict__ neg_idx,
                                                           float* __restrict__ recon,
                                                           float* __restrict__ mpart) {
    int b = blockIdx.x;
    int tid = threadIdx.x, wave = tid >> 6, lane = tid & 63;
    __shared__ __align__(16) float4 z4[E4];
    __shared__ float comp[NA];
    __shared__ __align__(16) float r_sh[E];
    __shared__ float red[12];
    __shared__ float dots[12];

    if (tid < E4) z4[tid] = ((const float4*)(z_s + (size_t)b * E))[tid];
    __syncthreads();

    for (int a = wave; a < NA; a += 12) {
        const float4* wr = (const float4*)(WredT + (size_t)a * E);
        float d = 0.f;
#pragma unroll
        for (int j = 0; j < 3; ++j)
            d += dot4(wr[lane + 64 * j], z4[lane + 64 * j]);
        d = wave_reduce_sum(d);
        if (lane == 0) comp[a] = d + b_red[a];
    }
    __syncthreads();

    if (wave == 0) {
        float v = (lane < NA) ? comp[lane] : -3.4e38f;
        float m = wave_reduce_max(v);
        m = __shfl(m, 0);
        float e = (lane < NA) ? expf(v - m) : 0.f;
        float ssum = wave_reduce_sum(e);
        ssum = __shfl(ssum, 0);
        if (lane < NA) comp[lane] = e / ssum;
    }
    __syncthreads();

    float r = 0.f;
    for (int a = 0; a < NA; ++a)
        r += comp[a] * aspect_W[(size_t)a * E + tid];
    recon[(size_t)b * E + tid] = r;
    r_sh[tid] = r;
    float sq = wave_reduce_sum(r * r);
    if (lane == 0) red[wave] = sq;
    __syncthreads();
    float tot = 0.f;
#pragma unroll
    for (int w = 0; w < 12; ++w) tot += red[w];
    float inv = 1.0f / fmaxf(sqrtf(tot), 1e-12f);

    if (wave <= NNEG) {
        int row = (wave == 0) ? b : neg_idx[b * NNEG + (wave - 1)];
        const float4* zr = (const float4*)(z_s + (size_t)row * E);
        const float4* rr = (const float4*)r_sh;
        float acc = 0.f;
#pragma unroll
        for (int j = 0; j < 3; ++j)
            acc += dot4(zr[lane + 64 * j], rr[lane + 64 * j]);
        acc = wave_reduce_sum(acc);
        if (lane == 0) dots[wave] = acc;
    }
    __syncthreads();
    if (tid == 0) {
        float pos = dots[0] * inv;
        float ssum = 0.f;
        for (int n = 1; n <= NNEG; ++n)
            ssum += fmaxf(1.f - pos + dots[n] * inv, 0.f);
        mpart[b] = ssum;
    }
}

// ---------------- K5: final scalar loss ----------------
__global__ __launch_bounds__(256) void loss_kernel(const float* __restrict__ Gpart,
                                                   const float* __restrict__ mpart,
                                                   float* __restrict__ loss_out) {
    int tid = threadIdx.x, wave = tid >> 6, lane = tid & 63;
    __shared__ float ra[4], rb[4];
    float fr = (tid < NA) ? Gpart[tid] : 0.f;
    fr = wave_reduce_sum(fr);
    if (lane == 0) ra[wave] = fr;
    float mp = mpart[tid];
    mp = wave_reduce_sum(mp);
    if (lane == 0) rb[wave] = mp;
    __syncthreads();
    if (tid == 0) {
        float frob = sqrtf(ra[0] + ra[1] + ra[2] + ra[3]);
        float msum = rb[0] + rb[1] + rb[2] + rb[3];
        loss_out[0] = frob + msum * (1.0f / (float)(B * NNEG));
    }
}

extern "C" void kernel_launch(void* const* d_in, const int* in_sizes, int n_in,
                              void* d_out, int out_size, void* d_ws, size_t ws_size,
                              hipStream_t stream) {
    const float* x        = (const float*)d_in[0];
    const float* W_att    = (const float*)d_in[1];
    const float* b_att    = (const float*)d_in[2];
    const float* W_red    = (const float*)d_in[3];
    const float* b_red    = (const float*)d_in[4];
    const float* aspect_W = (const float*)d_in[5];
    const int*   neg_idx  = (const int*)d_in[6];

    float* out   = (float*)d_out;
    float* z_s   = out;                       // [B,E]
    float* recon = out + (size_t)B * E;       // [B,E]
    float* loss  = out + (size_t)2 * B * E;   // [1]

    float* ws    = (float*)d_ws;
    float* q     = ws;                        // 2*B*E
    float* part2 = q + (size_t)2 * B * E;     // 8*B*E
    float* WredT = part2 + (size_t)8 * B * E; // NA*E
    float* Gpart = WredT + (size_t)NA * E;    // 32
    float* mpart = Gpart + 32;                // B
    float* endf  = mpart + B;

    size_t base_floats = (size_t)(endf - ws);
    size_t need = base_floats * sizeof(float) + (size_t)B * S * E * sizeof(__half);
    bool use16 = (ws_size >= need);
    __half* xh = (__half*)(ws + base_floats);

    if (use16) {
        mean_prep_kernel<1><<<2 * B + NA, 768, 0, stream>>>(x, W_red, aspect_W, q, WredT, Gpart, xh);
        qw_partial_kernel<<<dim3(4, 12, 8), 256, 0, stream>>>(q, W_att, part2);
        attn_kernel<1><<<B, 512, 0, stream>>>(x, xh, part2, b_att, z_s);
    } else {
        mean_prep_kernel<0><<<2 * B + NA, 768, 0, stream>>>(x, W_red, aspect_W, q, WredT, Gpart, xh);
        qw_partial_kernel<<<dim3(4, 12, 8), 256, 0, stream>>>(q, W_att, part2);
        attn_kernel<0><<<B, 512, 0, stream>>>(x, xh, part2, b_att, z_s);
    }
    recon_margin_kernel<<<B, 768, 0, stream>>>(z_s, WredT, b_red, aspect_W, neg_idx, recon, mpart);
    loss_kernel<<<1, 256, 0, stream>>>(Gpart, mpart, loss);
}